// Round 1
// baseline (5508.590 us; speedup 1.0000x reference)
//
#include <hip/hip_runtime.h>
#include <cstdint>
#include <cstddef>

// Problem dims (fixed by reference)
#define NT_   8192
#define DIN_  2048
#define H_    2048
#define C_    16
#define G_    2
#define D_    256
#define WA_   35
#define DECH_ 512

// JAX threefry config: 1 = partitionable (default since jax 0.4.36), 0 = original
#define RNG_PARTITIONABLE 1

// ---------------- threefry2x32 (Random123 / JAX-compatible) ----------------
__host__ __device__ inline void tf2x32(uint32_t k0, uint32_t k1,
                                       uint32_t x0, uint32_t x1,
                                       uint32_t& o0, uint32_t& o1) {
  const uint32_t ks2 = k0 ^ k1 ^ 0x1BD11BDAu;
  uint32_t ks[3] = {k0, k1, ks2};
  x0 += ks[0]; x1 += ks[1];
  const uint32_t R0[4] = {13u, 15u, 26u, 6u};
  const uint32_t R1[4] = {17u, 29u, 16u, 24u};
#pragma unroll
  for (int g = 0; g < 5; ++g) {
    const uint32_t* R = (g & 1) ? R1 : R0;
#pragma unroll
    for (int r = 0; r < 4; ++r) {
      x0 += x1;
      x1 = (x1 << R[r]) | (x1 >> (32u - R[r]));
      x1 ^= x0;
    }
    x0 += ks[(g + 1) % 3];
    x1 += ks[(g + 2) % 3] + (uint32_t)(g + 1);
  }
  o0 = x0; o1 = x1;
}

// ---------------- fp32 tiled GEMM: C = act(A@B + bias [+ gatherrow]) -------
// A (M,K) rm, B (K,N) rm, C (M,N) rm. M%128==0, N%128==0, K%16==0.
template <int RELU, int GATHER>
__global__ __launch_bounds__(256) void gemm128(
    const float* __restrict__ A, const float* __restrict__ B,
    const float* __restrict__ bias, float* __restrict__ Cm,
    int M, int N, int K,
    const int* __restrict__ gidx, const float* __restrict__ grow, int gld) {
  __shared__ float As[16][128];  // transposed: As[k][m]
  __shared__ float Bs[16][128];  // natural:    Bs[k][n]
  const int tid = threadIdx.x;
  const int n0 = blockIdx.x * 128;
  const int m0 = blockIdx.y * 128;
  const int tx = tid & 15, ty = tid >> 4;

  float acc[8][8];
#pragma unroll
  for (int i = 0; i < 8; ++i)
#pragma unroll
    for (int j = 0; j < 8; ++j) acc[i][j] = 0.f;

  for (int kt = 0; kt < K; kt += 16) {
#pragma unroll
    for (int l = 0; l < 2; ++l) {
      int f = tid + l * 256;            // 0..511 float4 tiles of A(128x16)
      int row = f >> 2, kc = (f & 3) << 2;
      const float4 v = *(const float4*)(A + (size_t)(m0 + row) * K + kt + kc);
      As[kc + 0][row] = v.x; As[kc + 1][row] = v.y;
      As[kc + 2][row] = v.z; As[kc + 3][row] = v.w;
    }
#pragma unroll
    for (int l = 0; l < 2; ++l) {
      int f = tid + l * 256;            // 0..511 float4 tiles of B(16x128)
      int kr = f >> 5, nc = (f & 31) << 2;
      *(float4*)&Bs[kr][nc] = *(const float4*)(B + (size_t)(kt + kr) * N + n0 + nc);
    }
    __syncthreads();
#pragma unroll
    for (int kk = 0; kk < 16; ++kk) {
      float a[8], b[8];
      *(float4*)&a[0] = *(float4*)&As[kk][ty * 8];
      *(float4*)&a[4] = *(float4*)&As[kk][ty * 8 + 4];
      *(float4*)&b[0] = *(float4*)&Bs[kk][tx * 8];
      *(float4*)&b[4] = *(float4*)&Bs[kk][tx * 8 + 4];
#pragma unroll
      for (int i = 0; i < 8; ++i)
#pragma unroll
        for (int j = 0; j < 8; ++j)
          acc[i][j] = fmaf(a[i], b[j], acc[i][j]);
    }
    __syncthreads();
  }

#pragma unroll
  for (int i = 0; i < 8; ++i) {
    const int row = m0 + ty * 8 + i;
    const float* gr = nullptr;
    if (GATHER) gr = grow + (size_t)gidx[row] * gld;
#pragma unroll
    for (int j = 0; j < 8; ++j) {
      const int col = n0 + tx * 8 + j;
      float v = acc[i][j] + bias[col];
      if (GATHER) v += gr[col];
      if (RELU) v = fmaxf(v, 0.f);
      Cm[(size_t)row * N + col] = v;
    }
  }
}

// ---------------- skinny GEMM: logits(M,16) = A(M,2048) @ W(2048,16)+b -----
__global__ __launch_bounds__(256) void skinny16_kernel(
    const float* __restrict__ A, const float* __restrict__ W,
    const float* __restrict__ bias, float* __restrict__ out) {
  __shared__ float row[H_];
  __shared__ float red[256];
  const int m = blockIdx.x;
  const float* a = A + (size_t)m * H_;
  for (int i = threadIdx.x; i < H_ / 4; i += 256)
    *(float4*)&row[i * 4] = *(const float4*)&a[i * 4];
  __syncthreads();
  const int c = threadIdx.x & 15, seg = threadIdx.x >> 4;
  const int k0 = seg * (H_ / 16);
  float p = 0.f;
  for (int i = 0; i < H_ / 16; ++i)
    p = fmaf(row[k0 + i], W[(size_t)(k0 + i) * C_ + c], p);
  red[threadIdx.x] = p;
  __syncthreads();
  if (threadIdx.x < C_) {
    float s = bias[threadIdx.x];
    for (int sg = 0; sg < 16; ++sg) s += red[sg * 16 + threadIdx.x];
    out[(size_t)m * C_ + threadIdx.x] = s;
  }
}

// ---------------- JAX categorical: argmax(logits + gumbel) -----------------
__global__ void sample_kernel(const float* __restrict__ logits,
                              int* __restrict__ s_out,
                              float* __restrict__ centers_out,
                              uint32_t ka, uint32_t kb, int which) {
  const int m = blockIdx.x * blockDim.x + threadIdx.x;
  if (m >= NT_) return;
  float best = -3.4e38f;
  int bi = 0;
#pragma unroll
  for (int c = 0; c < C_; ++c) {
    const uint32_t j = (uint32_t)(m * C_ + c);
    uint32_t o0, o1, bits;
#if RNG_PARTITIONABLE
    tf2x32(ka, kb, 0u, j, o0, o1);
    bits = o0 ^ o1;
#else
    const uint32_t HALF = (uint32_t)(NT_ * C_) / 2u;
    if (j < HALF) { tf2x32(ka, kb, j, j + HALF, o0, o1); bits = o0; }
    else          { tf2x32(ka, kb, j - HALF, j, o0, o1); bits = o1; }
#endif
    const uint32_t fb = (bits >> 9) | 0x3f800000u;
    float u = __uint_as_float(fb) - 1.0f;      // [0,1) at 2^-23 grid
    u = fmaxf(1.17549435e-38f, u);             // == u*(1-tiny)+tiny then max
    const float gmb = -logf(-logf(u));
    const float z = gmb + logits[(size_t)m * C_ + c];
    if (z > best) { best = z; bi = c; }        // first-max, matches jnp.argmax
  }
  s_out[m] = bi;
  centers_out[(size_t)m * G_ + which] = (float)bi;
}

// ---------------- dec_in gather: codebook rows -----------------------------
__global__ void gather_dec_kernel(const float* __restrict__ codebook,
                                  const int* __restrict__ s1,
                                  const int* __restrict__ s2,
                                  float* __restrict__ dec_in) {
  const int idx = blockIdx.x * blockDim.x + threadIdx.x;  // over NT_*512
  const int m = idx >> 9, d = idx & 511;
  const int g = d >> 8, dd = d & 255;
  const int s = g ? s2[m] : s1[m];
  dec_in[idx] = codebook[(size_t)(g * C_ + s) * D_ + dd];
}

// ---------------- final: decoded + gathered sampled offsets ----------------
__global__ __launch_bounds__(320) void final_kernel(
    const float* __restrict__ o2,     // (NT_, 2048)
    const float* __restrict__ wo3,    // (2048, 1120)
    const float* __restrict__ bo3,    // (1120)
    const float* __restrict__ dec_h,  // (NT_, 512)
    const float* __restrict__ wd2,    // (512, 35)
    const float* __restrict__ bd2,    // (35)
    const int* __restrict__ s1, const int* __restrict__ s2,
    float* __restrict__ out_pred, float* __restrict__ out_dec) {
  __shared__ float orow[H_];
  __shared__ float drow[DECH_];
  const int m = blockIdx.x;
  {
    const float* op = o2 + (size_t)m * H_;
    for (int i = threadIdx.x; i < H_ / 4; i += 320)
      *(float4*)&orow[i * 4] = *(const float4*)&op[i * 4];
    const float* dp = dec_h + (size_t)m * DECH_;
    for (int i = threadIdx.x; i < DECH_ / 4; i += 320)
      *(float4*)&drow[i * 4] = *(const float4*)&dp[i * 4];
  }
  __syncthreads();
  const int a1 = s1[m], a2 = s2[m];
  const int c = threadIdx.x >> 3, g = threadIdx.x & 7;
  float poff = 0.f, pdec = 0.f;
  if (c < WA_) {
    const int col1 = a1 * WA_ + c;
    const int col2 = G_ == 2 ? (C_ * WA_ + a2 * WA_ + c) : 0;  // 560 + ...
    for (int i = 0; i < H_ / 8; ++i) {
      const int k = g * (H_ / 8) + i;
      const float ov = orow[k];
      poff = fmaf(ov, wo3[(size_t)k * (G_ * C_ * WA_) + col1], poff);
      poff = fmaf(ov, wo3[(size_t)k * (G_ * C_ * WA_) + col2], poff);
    }
    for (int i = 0; i < DECH_ / 8; ++i) {
      const int k = g * (DECH_ / 8) + i;
      pdec = fmaf(drow[k], wd2[(size_t)k * WA_ + c], pdec);
    }
  }
#pragma unroll
  for (int off = 1; off < 8; off <<= 1) {
    poff += __shfl_xor(poff, off);
    pdec += __shfl_xor(pdec, off);
  }
  if (c < WA_ && g == 0) {
    const float dec = pdec + bd2[c];
    const float so = poff + bo3[a1 * WA_ + c] + bo3[C_ * WA_ + a2 * WA_ + c];
    out_dec[(size_t)m * WA_ + c] = dec;
    out_pred[(size_t)m * WA_ + c] = dec + so;
  }
}

// ---------------------------------------------------------------------------
extern "C" void kernel_launch(void* const* d_in, const int* in_sizes, int n_in,
                              void* d_out, int out_size, void* d_ws, size_t ws_size,
                              hipStream_t stream) {
  const float* x    = (const float*)d_in[0];
  const float* w11  = (const float*)d_in[1];
  const float* b11  = (const float*)d_in[2];
  const float* w12  = (const float*)d_in[3];
  const float* b12  = (const float*)d_in[4];
  const float* w13  = (const float*)d_in[5];
  const float* b13  = (const float*)d_in[6];
  const float* w21  = (const float*)d_in[7];
  const float* b21  = (const float*)d_in[8];
  const float* w22  = (const float*)d_in[9];
  const float* b22  = (const float*)d_in[10];
  const float* wo1  = (const float*)d_in[11];
  const float* bo1  = (const float*)d_in[12];
  const float* wo2  = (const float*)d_in[13];
  const float* bo2  = (const float*)d_in[14];
  const float* wo3  = (const float*)d_in[15];
  const float* bo3  = (const float*)d_in[16];
  const float* cbk  = (const float*)d_in[17];
  const float* wd1  = (const float*)d_in[18];
  const float* bd1  = (const float*)d_in[19];
  const float* wd2  = (const float*)d_in[20];
  const float* bd2  = (const float*)d_in[21];

  float* out = (float*)d_out;
  float* out_pred = out;                                  // (NT_,35)
  float* out_dec  = out + (size_t)NT_ * WA_;              // (NT_,35)
  float* out_l1   = out + (size_t)2 * NT_ * WA_;          // (NT_,16)
  float* out_l2   = out_l1 + (size_t)NT_ * C_;            // (NT_,16)
  float* out_sc   = out_l2 + (size_t)NT_ * C_;            // (NT_,2)

  float* W0   = (float*)d_ws;                             // (NT_,2048)
  float* W1   = W0 + (size_t)NT_ * H_;                    // (NT_,2048)
  float* Wdec = W1 + (size_t)NT_ * H_;                    // (NT_,512)
  float* Wdh  = Wdec + (size_t)NT_ * DECH_;               // (NT_,512)
  int*   S1   = (int*)(Wdh + (size_t)NT_ * DECH_);
  int*   S2   = S1 + NT_;

  // subkeys of jax.random.split(jax.random.key(42)); key data = [0,42]
  uint32_t k1a, k1b, k2a, k2b;
#if RNG_PARTITIONABLE
  tf2x32(0u, 42u, 0u, 0u, k1a, k1b);
  tf2x32(0u, 42u, 0u, 1u, k2a, k2b);
#else
  {
    uint32_t A0, B0, A1, B1;
    tf2x32(0u, 42u, 0u, 2u, A0, B0);
    tf2x32(0u, 42u, 1u, 3u, A1, B1);
    k1a = A0; k1b = A1; k2a = B0; k2b = B1;
  }
#endif

  const dim3 blk(256);
  const dim3 gHH(H_ / 128, NT_ / 128);      // (16,64)
  const dim3 gDec(DECH_ / 128, NT_ / 128);  // (4,64)

  // bin1 path
  gemm128<1, 0><<<gHH, blk, 0, stream>>>(x,  w11, b11, W0, NT_, H_, DIN_, nullptr, nullptr, 0);
  gemm128<1, 0><<<gHH, blk, 0, stream>>>(W0, w12, b12, W1, NT_, H_, H_,   nullptr, nullptr, 0);
  skinny16_kernel<<<NT_, 256, 0, stream>>>(W1, w13, b13, out_l1);
  sample_kernel<<<NT_ / 256, 256, 0, stream>>>(out_l1, S1, out_sc, k1a, k1b, 0);

  // bin2 path: h2 = relu(x @ w21[:2048] + w21[2048+s1] + b21)
  gemm128<1, 1><<<gHH, blk, 0, stream>>>(x, w21, b21, W0, NT_, H_, DIN_,
                                         S1, w21 + (size_t)DIN_ * H_, H_);
  skinny16_kernel<<<NT_, 256, 0, stream>>>(W0, w22, b22, out_l2);
  sample_kernel<<<NT_ / 256, 256, 0, stream>>>(out_l2, S2, out_sc, k2a, k2b, 1);

  // offsets path (full 1120-wide GEMM avoided; sampled columns fused later)
  gemm128<1, 0><<<gHH, blk, 0, stream>>>(x,  wo1, bo1, W0, NT_, H_, DIN_, nullptr, nullptr, 0);
  gemm128<1, 0><<<gHH, blk, 0, stream>>>(W0, wo2, bo2, W1, NT_, H_, H_,   nullptr, nullptr, 0);

  // decoder
  gather_dec_kernel<<<(NT_ * DECH_) / 256, 256, 0, stream>>>(cbk, S1, S2, Wdec);
  gemm128<1, 0><<<gDec, blk, 0, stream>>>(Wdec, wd1, bd1, Wdh, NT_, DECH_, DECH_, nullptr, nullptr, 0);

  // final: decoded, predicted = decoded + sampled_offsets
  final_kernel<<<NT_, 320, 0, stream>>>(W1, wo3, bo3, Wdh, wd2, bd2, S1, S2,
                                        out_pred, out_dec);
  (void)in_sizes; (void)n_in; (void)out_size; (void)ws_size;
}

// Round 2
// 1297.503 us; speedup vs baseline: 4.2455x; 4.2455x over previous
//
#include <hip/hip_runtime.h>
#include <cstdint>
#include <cstddef>

// Problem dims (fixed by reference)
#define NT_   8192
#define DIN_  2048
#define H_    2048
#define C_    16
#define G_    2
#define D_    256
#define WA_   35
#define DECH_ 512
#define NPAD_ 1152   // 1120 padded to 9*128

typedef _Float16 f16;
typedef _Float16 h4 __attribute__((ext_vector_type(4)));
typedef _Float16 h8 __attribute__((ext_vector_type(8)));
typedef float fx4 __attribute__((ext_vector_type(4)));

typedef __attribute__((address_space(1))) const void gvoid_t;
typedef __attribute__((address_space(3))) void lvoid_t;

// async global->LDS, 16B per lane; LDS dest = wave-uniform base + lane*16
__device__ __forceinline__ void gld16(const void* g, void* l) {
  __builtin_amdgcn_global_load_lds((gvoid_t*)(uintptr_t)g,
                                   (lvoid_t*)(uint32_t)(uintptr_t)l, 16, 0, 0);
}

// ---------------- threefry2x32 (Random123 / JAX-compatible) ----------------
__host__ __device__ inline void tf2x32(uint32_t k0, uint32_t k1,
                                       uint32_t x0, uint32_t x1,
                                       uint32_t& o0, uint32_t& o1) {
  const uint32_t ks2 = k0 ^ k1 ^ 0x1BD11BDAu;
  uint32_t ks[3] = {k0, k1, ks2};
  x0 += ks[0]; x1 += ks[1];
  const uint32_t R0[4] = {13u, 15u, 26u, 6u};
  const uint32_t R1[4] = {17u, 29u, 16u, 24u};
#pragma unroll
  for (int g = 0; g < 5; ++g) {
    const uint32_t* R = (g & 1) ? R1 : R0;
#pragma unroll
    for (int r = 0; r < 4; ++r) {
      x0 += x1;
      x1 = (x1 << R[r]) | (x1 >> (32u - R[r]));
      x1 ^= x0;
    }
    x0 += ks[(g + 1) % 3];
    x1 += ks[(g + 2) % 3] + (uint32_t)(g + 1);
  }
  o0 = x0; o1 = x1;
}

// ============== MFMA GEMM: C = act(A@B^T + bias [+ gatherrow]) =============
// A: (M,K) f16 hi[/lo]  (or fp32 when ACONV, split in-kernel)
// B: (N,K) f16 hi[/lo]  (pre-transposed weights)
// C: (M,N) f16 hi[/lo]. 128x128 tile, BK=32, 4 waves, 16x16x32 MFMA.
template <int TERMS, int RELU, int GATHER, int WLO, int ACONV>
__global__ __launch_bounds__(256, 2) void mfma_gemm(
    const void* __restrict__ Ahi_, const void* __restrict__ Alo_,
    const f16* __restrict__ Bhi, const f16* __restrict__ Blo,
    const float* __restrict__ bias,
    f16* __restrict__ Chi, f16* __restrict__ Clo,
    int M, int N, int K,
    const int* __restrict__ gidx, const float* __restrict__ grow, int gld) {
  constexpr int NTILE = (TERMS == 3) ? 4 : 2;
  __shared__ f16 lds[NTILE * 4096];  // tiles of 128x32 f16 (8KB each)
  f16* sAh = lds;
  f16* sBh = lds + 4096;
  f16* sAl = (TERMS == 3) ? lds + 2 * 4096 : lds;
  f16* sBl = (TERMS == 3) ? lds + 3 * 4096 : lds;

  const int tid  = threadIdx.x;
  const int wave = tid >> 6;
  const int lane = tid & 63;
  const int m0 = blockIdx.y * 128;
  const int n0 = blockIdx.x * 128;
  const int wm = (wave >> 1) * 64;
  const int wn = (wave & 1) * 64;
  const int lr = lane & 15;          // row/col within a 16-tile
  const int lk = (lane >> 4) * 8;    // k-slice base

  fx4 acc[4][4];
#pragma unroll
  for (int i = 0; i < 4; ++i)
#pragma unroll
    for (int j = 0; j < 4; ++j) acc[i][j] = (fx4){0.f, 0.f, 0.f, 0.f};

  const int sb = wave * 2048 + (lane << 4);  // byte offset of chunk c=0 in tile

  for (int kt = 0; kt < K; kt += 32) {
    // ---- stage B tiles (always async GLD; linear LDS) ----
#pragma unroll
    for (int c = 0; c < 2; ++c) {
      const int boff = sb + c * 1024;
      const int row  = boff >> 6;        // 64B per tile row
      const int col  = (boff & 63) >> 1; // f16 col
      gld16(Bhi + (size_t)(n0 + row) * K + kt + col, sBh + (wave * 2 + c) * 512);
      if constexpr (TERMS == 3)
        gld16(Blo + (size_t)(n0 + row) * K + kt + col, sBl + (wave * 2 + c) * 512);
    }
    // ---- stage A tiles ----
    if constexpr (ACONV) {
      const float* A32 = (const float*)Ahi_;
#pragma unroll
      for (int p = 0; p < 4; ++p) {
        const int e   = (tid + p * 256) << 2;  // element idx in 128x32 tile
        const int row = e >> 5, col = e & 31;
        const float4 v = *(const float4*)(A32 + (size_t)(m0 + row) * K + kt + col);
        h4 hh, ll;
        hh.x = (f16)v.x; ll.x = (f16)(v.x - (float)hh.x);
        hh.y = (f16)v.y; ll.y = (f16)(v.y - (float)hh.y);
        hh.z = (f16)v.z; ll.z = (f16)(v.z - (float)hh.z);
        hh.w = (f16)v.w; ll.w = (f16)(v.w - (float)hh.w);
        *(h4*)&sAh[row * 32 + col] = hh;
        if constexpr (TERMS == 3) *(h4*)&sAl[row * 32 + col] = ll;
      }
    } else {
      const f16* Ah = (const f16*)Ahi_;
      const f16* Al = (const f16*)Alo_;
#pragma unroll
      for (int c = 0; c < 2; ++c) {
        const int boff = sb + c * 1024;
        const int row  = boff >> 6;
        const int col  = (boff & 63) >> 1;
        gld16(Ah + (size_t)(m0 + row) * K + kt + col, sAh + (wave * 2 + c) * 512);
        if constexpr (TERMS == 3)
          gld16(Al + (size_t)(m0 + row) * K + kt + col, sAl + (wave * 2 + c) * 512);
      }
    }
    __syncthreads();  // drains vmcnt+lgkmcnt, then barrier

    h8 ah[4], bh[4];
#pragma unroll
    for (int t = 0; t < 4; ++t) {
      ah[t] = *(const h8*)&sAh[(wm + t * 16 + lr) * 32 + lk];
      bh[t] = *(const h8*)&sBh[(wn + t * 16 + lr) * 32 + lk];
    }
    if constexpr (TERMS == 3) {
      h8 al[4], bl[4];
#pragma unroll
      for (int t = 0; t < 4; ++t) {
        al[t] = *(const h8*)&sAl[(wm + t * 16 + lr) * 32 + lk];
        bl[t] = *(const h8*)&sBl[(wn + t * 16 + lr) * 32 + lk];
      }
#pragma unroll
      for (int i = 0; i < 4; ++i)
#pragma unroll
        for (int j = 0; j < 4; ++j) {
          acc[i][j] = __builtin_amdgcn_mfma_f32_16x16x32_f16(ah[i], bh[j], acc[i][j], 0, 0, 0);
          acc[i][j] = __builtin_amdgcn_mfma_f32_16x16x32_f16(ah[i], bl[j], acc[i][j], 0, 0, 0);
          acc[i][j] = __builtin_amdgcn_mfma_f32_16x16x32_f16(al[i], bh[j], acc[i][j], 0, 0, 0);
        }
    } else {
#pragma unroll
      for (int i = 0; i < 4; ++i)
#pragma unroll
        for (int j = 0; j < 4; ++j)
          acc[i][j] = __builtin_amdgcn_mfma_f32_16x16x32_f16(ah[i], bh[j], acc[i][j], 0, 0, 0);
    }
    __syncthreads();
  }

  // ---- epilogue: D[(lane>>4)*4+q][lane&15] per 16x16 fragment ----
  const int rq = (lane >> 4) * 4;
#pragma unroll
  for (int i = 0; i < 4; ++i) {
#pragma unroll
    for (int q = 0; q < 4; ++q) {
      const int row = m0 + wm + i * 16 + rq + q;
      const float* gr = nullptr;
      if constexpr (GATHER) gr = grow + (size_t)gidx[row] * gld;
#pragma unroll
      for (int j = 0; j < 4; ++j) {
        const int col = n0 + wn + j * 16 + lr;
        float v = acc[i][j][q];
        if (bias) v += bias[col];
        if constexpr (GATHER) v += gr[col];
        if constexpr (RELU) v = fmaxf(v, 0.f);
        const f16 hh = (f16)v;
        Chi[(size_t)row * N + col] = hh;
        if constexpr (WLO) Clo[(size_t)row * N + col] = (f16)(v - (float)hh);
      }
    }
  }
}

// ====== weight transpose+convert: (K,N) fp32 -> (Npad,K) f16 hi[/lo] =======
template <int SPLIT>
__global__ __launch_bounds__(256) void wtransT(
    const float* __restrict__ src, f16* __restrict__ hi, f16* __restrict__ lo,
    int K, int N, int Npad) {
  __shared__ float t[32][33];
  const int bn = blockIdx.x * 32;  // n tile
  const int bk = blockIdx.y * 32;  // k tile
  const int tx = threadIdx.x & 31, ty = threadIdx.x >> 5;
#pragma unroll
  for (int r = ty; r < 32; r += 8) {
    const float v = (bn + tx < N) ? src[(size_t)(bk + r) * N + bn + tx] : 0.f;
    t[tx][r] = v;  // t[n_local][k_local]
  }
  __syncthreads();
#pragma unroll
  for (int r = ty; r < 32; r += 8) {
    const float v = t[r][tx];
    const f16 hh = (f16)v;
    hi[(size_t)(bn + r) * K + bk + tx] = hh;
    if (SPLIT) lo[(size_t)(bn + r) * K + bk + tx] = (f16)(v - (float)hh);
  }
}

// ====== skinny logits: (M,16) = (hi+lo)(M,2048) @ W(2048,16) + b ============
__global__ __launch_bounds__(256) void skinny16_hl(
    const f16* __restrict__ Ahi, const f16* __restrict__ Alo,
    const float* __restrict__ W, const float* __restrict__ bias,
    float* __restrict__ out) {
  __shared__ float row[H_];
  __shared__ float red[256];
  const int m = blockIdx.x;
  const f16* ah = Ahi + (size_t)m * H_;
  const f16* al = Alo + (size_t)m * H_;
  for (int i = threadIdx.x; i < H_ / 4; i += 256) {
    const h4 hh = ((const h4*)ah)[i];
    const h4 ll = ((const h4*)al)[i];
    row[i * 4 + 0] = (float)hh.x + (float)ll.x;
    row[i * 4 + 1] = (float)hh.y + (float)ll.y;
    row[i * 4 + 2] = (float)hh.z + (float)ll.z;
    row[i * 4 + 3] = (float)hh.w + (float)ll.w;
  }
  __syncthreads();
  const int c = threadIdx.x & 15, seg = threadIdx.x >> 4;
  const int k0 = seg * (H_ / 16);
  float p = 0.f;
  for (int i = 0; i < H_ / 16; ++i)
    p = fmaf(row[k0 + i], W[(size_t)(k0 + i) * C_ + c], p);
  red[threadIdx.x] = p;
  __syncthreads();
  if (threadIdx.x < C_) {
    float s = bias[threadIdx.x];
    for (int sg = 0; sg < 16; ++sg) s += red[sg * 16 + threadIdx.x];
    out[(size_t)m * C_ + threadIdx.x] = s;
  }
}

// ---------------- JAX categorical: argmax(logits + gumbel) -----------------
__global__ void sample_kernel(const float* __restrict__ logits,
                              int* __restrict__ s_out,
                              float* __restrict__ centers_out,
                              uint32_t ka, uint32_t kb, int which) {
  const int m = blockIdx.x * blockDim.x + threadIdx.x;
  if (m >= NT_) return;
  float best = -3.4e38f;
  int bi = 0;
#pragma unroll
  for (int c = 0; c < C_; ++c) {
    const uint32_t j = (uint32_t)(m * C_ + c);
    uint32_t o0, o1;
    tf2x32(ka, kb, 0u, j, o0, o1);
    const uint32_t bits = o0 ^ o1;
    const uint32_t fb = (bits >> 9) | 0x3f800000u;
    float u = __uint_as_float(fb) - 1.0f;
    u = fmaxf(1.17549435e-38f, u);
    const float gmb = -logf(-logf(u));
    const float z = gmb + logits[(size_t)m * C_ + c];
    if (z > best) { best = z; bi = c; }
  }
  s_out[m] = bi;
  centers_out[(size_t)m * G_ + which] = (float)bi;
}

// ---------------- dec_in gather: codebook rows -> f16 ----------------------
__global__ void gather_dec_kernel(const float* __restrict__ codebook,
                                  const int* __restrict__ s1,
                                  const int* __restrict__ s2,
                                  f16* __restrict__ dec_in) {
  const int idx = blockIdx.x * blockDim.x + threadIdx.x;  // over NT_*512
  const int m = idx >> 9, d = idx & 511;
  const int g = d >> 8, dd = d & 255;
  const int s = g ? s2[m] : s1[m];
  dec_in[idx] = (f16)codebook[(size_t)(g * C_ + s) * D_ + dd];
}

// ------- final: decoded = dec_h@wd2+bd2 ; pred = decoded + P gather --------
__global__ __launch_bounds__(320) void final2(
    const f16* __restrict__ P,     // (NT_, NPAD_)
    const float* __restrict__ bo3, // (1120)
    const f16* __restrict__ dech,  // (NT_, 512)
    const float* __restrict__ wd2, const float* __restrict__ bd2,
    const int* __restrict__ s1, const int* __restrict__ s2,
    float* __restrict__ out_pred, float* __restrict__ out_dec) {
  __shared__ float drow[DECH_];
  const int m = blockIdx.x;
  for (int i = threadIdx.x; i < DECH_; i += 320)
    drow[i] = (float)dech[(size_t)m * DECH_ + i];
  __syncthreads();
  const int a1 = s1[m], a2 = s2[m];
  const int c = threadIdx.x >> 3, g = threadIdx.x & 7;
  float pdec = 0.f;
  if (c < WA_) {
    for (int i = 0; i < DECH_ / 8; ++i) {
      const int k = g * (DECH_ / 8) + i;
      pdec = fmaf(drow[k], wd2[(size_t)k * WA_ + c], pdec);
    }
  }
#pragma unroll
  for (int off = 1; off < 8; off <<= 1) pdec += __shfl_xor(pdec, off);
  if (c < WA_ && g == 0) {
    const float dec = pdec + bd2[c];
    const float soff = (float)P[(size_t)m * NPAD_ + a1 * WA_ + c]
                     + (float)P[(size_t)m * NPAD_ + C_ * WA_ + a2 * WA_ + c]
                     + bo3[a1 * WA_ + c] + bo3[C_ * WA_ + a2 * WA_ + c];
    out_dec[(size_t)m * WA_ + c] = dec;
    out_pred[(size_t)m * WA_ + c] = dec + soff;
  }
}

// ---------------------------------------------------------------------------
extern "C" void kernel_launch(void* const* d_in, const int* in_sizes, int n_in,
                              void* d_out, int out_size, void* d_ws, size_t ws_size,
                              hipStream_t stream) {
  const float* x    = (const float*)d_in[0];
  const float* w11  = (const float*)d_in[1];
  const float* b11  = (const float*)d_in[2];
  const float* w12  = (const float*)d_in[3];
  const float* b12  = (const float*)d_in[4];
  const float* w13  = (const float*)d_in[5];
  const float* b13  = (const float*)d_in[6];
  const float* w21  = (const float*)d_in[7];
  const float* b21  = (const float*)d_in[8];
  const float* w22  = (const float*)d_in[9];
  const float* b22  = (const float*)d_in[10];
  const float* wo1  = (const float*)d_in[11];
  const float* bo1  = (const float*)d_in[12];
  const float* wo2  = (const float*)d_in[13];
  const float* bo2  = (const float*)d_in[14];
  const float* wo3  = (const float*)d_in[15];
  const float* bo3  = (const float*)d_in[16];
  const float* cbk  = (const float*)d_in[17];
  const float* wd1  = (const float*)d_in[18];
  const float* bd1  = (const float*)d_in[19];
  const float* wd2  = (const float*)d_in[20];
  const float* bd2  = (const float*)d_in[21];

  float* out = (float*)d_out;
  float* out_pred = out;                                  // (NT_,35)
  float* out_dec  = out + (size_t)NT_ * WA_;              // (NT_,35)
  float* out_l1   = out + (size_t)2 * NT_ * WA_;          // (NT_,16)
  float* out_l2   = out_l1 + (size_t)NT_ * C_;            // (NT_,16)
  float* out_sc   = out_l2 + (size_t)NT_ * C_;            // (NT_,2)

  // workspace: 4 activation buffers (NT x 2048 f16 = 32MiB) + weight slot
  const size_t AB = (size_t)NT_ * H_;
  f16* H1a = (f16*)d_ws;
  f16* H1b = H1a + AB;
  f16* Ha  = H1b + AB;
  f16* Hb  = Ha + AB;
  f16* WH  = Hb + AB;                      // 2048*2048 f16 (8 MiB)
  f16* WL  = WH + (size_t)H_ * H_;
  int* S1  = (int*)(WL + (size_t)H_ * H_);
  int* S2  = S1 + NT_;

  f16* P     = Ha;                          // (NT_, NPAD_) f16 (18 MiB)
  f16* DECIN = Hb;                          // (NT_, 512)
  f16* DECH  = Hb + (size_t)NT_ * DECH_;    // (NT_, 512)

  // subkeys of jax.random.split(jax.random.key(42)); key data = [0,42]
  uint32_t k1a, k1b, k2a, k2b;
  tf2x32(0u, 42u, 0u, 0u, k1a, k1b);
  tf2x32(0u, 42u, 0u, 1u, k2a, k2b);

  const dim3 b256(256);
  const dim3 gW(H_ / 32, H_ / 32);          // (64,64)
  const dim3 gWo3(NPAD_ / 32, H_ / 32);     // (36,64)
  const dim3 gWd1(DECH_ / 32, DECH_ / 32);  // (16,16)
  const dim3 gG(H_ / 128, NT_ / 128);       // (16,64)
  const dim3 gP(NPAD_ / 128, NT_ / 128);    // (9,64)
  const dim3 gD(DECH_ / 128, NT_ / 128);    // (4,64)

  // ---- bin1: h1 = relu(x@w11+b11); h = relu(h1@w12+b12); l1 = h@w13+b13
  wtransT<1><<<gW, b256, 0, stream>>>(w11, WH, WL, H_, H_, H_);
  mfma_gemm<3, 1, 0, 1, 1><<<gG, b256, 0, stream>>>(
      x, nullptr, WH, WL, b11, H1a, H1b, NT_, H_, DIN_, nullptr, nullptr, 0);
  wtransT<1><<<gW, b256, 0, stream>>>(w12, WH, WL, H_, H_, H_);
  mfma_gemm<3, 1, 0, 1, 0><<<gG, b256, 0, stream>>>(
      H1a, H1b, WH, WL, b12, Ha, Hb, NT_, H_, H_, nullptr, nullptr, 0);
  skinny16_hl<<<NT_, 256, 0, stream>>>(Ha, Hb, w13, b13, out_l1);
  sample_kernel<<<NT_ / 256, 256, 0, stream>>>(out_l1, S1, out_sc, k1a, k1b, 0);

  // ---- bin2: h2 = relu(x@w21[:2048] + w21[2048+s1] + b21); l2 = h2@w22+b22
  wtransT<1><<<gW, b256, 0, stream>>>(w21, WH, WL, H_, H_, H_);
  mfma_gemm<3, 1, 1, 1, 1><<<gG, b256, 0, stream>>>(
      x, nullptr, WH, WL, b21, Ha, Hb, NT_, H_, DIN_,
      S1, w21 + (size_t)DIN_ * H_, H_);
  skinny16_hl<<<NT_, 256, 0, stream>>>(Ha, Hb, w22, b22, out_l2);
  sample_kernel<<<NT_ / 256, 256, 0, stream>>>(out_l2, S2, out_sc, k2a, k2b, 1);

  // ---- offsets: o = relu(x@wo1+bo1); o2 = relu(o@wo2+bo2); P = o2@wo3
  wtransT<0><<<gW, b256, 0, stream>>>(wo1, WH, nullptr, H_, H_, H_);
  mfma_gemm<1, 1, 0, 0, 1><<<gG, b256, 0, stream>>>(
      x, nullptr, WH, nullptr, bo1, H1a, nullptr, NT_, H_, DIN_, nullptr, nullptr, 0);
  wtransT<0><<<gW, b256, 0, stream>>>(wo2, WH, nullptr, H_, H_, H_);
  mfma_gemm<1, 1, 0, 0, 0><<<gG, b256, 0, stream>>>(
      H1a, nullptr, WH, nullptr, bo2, H1b, nullptr, NT_, H_, H_, nullptr, nullptr, 0);
  wtransT<0><<<gWo3, b256, 0, stream>>>(wo3, WH, nullptr, H_, G_ * C_ * WA_, NPAD_);
  mfma_gemm<1, 0, 0, 0, 0><<<gP, b256, 0, stream>>>(
      H1b, nullptr, WH, nullptr, nullptr, P, nullptr, NT_, NPAD_, H_, nullptr, nullptr, 0);

  // ---- decoder: dec_h = relu(dec_in@wd1+bd1)
  gather_dec_kernel<<<(NT_ * DECH_) / 256, 256, 0, stream>>>(cbk, S1, S2, DECIN);
  wtransT<0><<<gWd1, b256, 0, stream>>>(wd1, WH, nullptr, DECH_, DECH_, DECH_);
  mfma_gemm<1, 1, 0, 0, 0><<<gD, b256, 0, stream>>>(
      DECIN, nullptr, WH, nullptr, bd1, DECH, nullptr, NT_, DECH_, DECH_, nullptr, nullptr, 0);

  // ---- final combine
  final2<<<NT_, 320, 0, stream>>>(P, bo3, DECH, wd2, bd2, S1, S2, out_pred, out_dec);

  (void)in_sizes; (void)n_in; (void)out_size; (void)ws_size;
}

// Round 3
// 1101.799 us; speedup vs baseline: 4.9996x; 1.1776x over previous
//
#include <hip/hip_runtime.h>
#include <cstdint>
#include <cstddef>

// Problem dims (fixed by reference)
#define NT_   8192
#define DIN_  2048
#define H_    2048
#define C_    16
#define G_    2
#define D_    256
#define WA_   35
#define DECH_ 512
#define NPAD_ 1152   // 1120 padded to 9*128

typedef _Float16 f16;
typedef _Float16 h4 __attribute__((ext_vector_type(4)));
typedef _Float16 h8 __attribute__((ext_vector_type(8)));
typedef float fx4 __attribute__((ext_vector_type(4)));

typedef __attribute__((address_space(1))) const void gvoid_t;
typedef __attribute__((address_space(3))) void lvoid_t;

// async global->LDS, 16B per lane; LDS dest = wave-uniform base + lane*16
__device__ __forceinline__ void gld16(const void* g, void* l) {
  __builtin_amdgcn_global_load_lds((gvoid_t*)(uintptr_t)g,
                                   (lvoid_t*)(uint32_t)(uintptr_t)l, 16, 0, 0);
}

template <int N>
__device__ __forceinline__ void waitvm() {
  if constexpr (N == 8)      asm volatile("s_waitcnt vmcnt(8)" ::: "memory");
  else if constexpr (N == 6) asm volatile("s_waitcnt vmcnt(6)" ::: "memory");
  else if constexpr (N == 4) asm volatile("s_waitcnt vmcnt(4)" ::: "memory");
  else if constexpr (N == 2) asm volatile("s_waitcnt vmcnt(2)" ::: "memory");
  else                       asm volatile("s_waitcnt vmcnt(0)" ::: "memory");
}

// ---------------- threefry2x32 (Random123 / JAX-compatible) ----------------
__host__ __device__ inline void tf2x32(uint32_t k0, uint32_t k1,
                                       uint32_t x0, uint32_t x1,
                                       uint32_t& o0, uint32_t& o1) {
  const uint32_t ks2 = k0 ^ k1 ^ 0x1BD11BDAu;
  uint32_t ks[3] = {k0, k1, ks2};
  x0 += ks[0]; x1 += ks[1];
  const uint32_t R0[4] = {13u, 15u, 26u, 6u};
  const uint32_t R1[4] = {17u, 29u, 16u, 24u};
#pragma unroll
  for (int g = 0; g < 5; ++g) {
    const uint32_t* R = (g & 1) ? R1 : R0;
#pragma unroll
    for (int r = 0; r < 4; ++r) {
      x0 += x1;
      x1 = (x1 << R[r]) | (x1 >> (32u - R[r]));
      x1 ^= x0;
    }
    x0 += ks[(g + 1) % 3];
    x1 += ks[(g + 2) % 3] + (uint32_t)(g + 1);
  }
  o0 = x0; o1 = x1;
}

// ============ 256x256-tile MFMA GEMM, BK=32, 8 waves, deep prefetch ========
// A: (M,K) f16 hi[/lo] (or fp32 when ACONV; split in-kernel at ds_write)
// B: (N,K) f16 hi[/lo] (pre-transposed weights)
// C = act(A@B^T + bias [+gatherrow]) -> f16 hi[/lo]
// LDS: double-buffered; XOR-swizzled granules (phys = g ^ ((row>>1)&3)),
// applied on the gld16 SOURCE address and on the ds_read address (rule #21).
template <int TERMS, int RELU, int GATHER, int WLO, int ACONV>
__global__ __launch_bounds__(512, 2) void gemm256(
    const void* __restrict__ Ahi_, const void* __restrict__ Alo_,
    const f16* __restrict__ Bhi, const f16* __restrict__ Blo,
    const float* __restrict__ bias,
    f16* __restrict__ Chi, f16* __restrict__ Clo,
    int M, int N, int K,
    const int* __restrict__ gidx, const float* __restrict__ growp, int gldw) {
  extern __shared__ f16 lds[];
  constexpr int NREG = (TERMS == 3) ? 4 : 2;   // regions: Ah[,Al],Bh[,Bl]
  constexpr int BS   = NREG * 8192;            // f16 per buffer (16KB regions)
  constexpr int NGLD = (TERMS == 3) ? (ACONV ? 4 : 8) : (ACONV ? 2 : 4);

  const int tid  = threadIdx.x;
  const int wave = tid >> 6;
  const int lane = tid & 63;
  const int lr   = lane & 15;

  // bijective XCD swizzle (nwg % 8 == 0 for all our shapes)
  const int nb  = N >> 8;
  const int nwg = (int)gridDim.x;
  const int qq  = nwg >> 3;
  const int sw  = ((int)blockIdx.x & 7) * qq + ((int)blockIdx.x >> 3);
  const int by  = sw / nb, bx = sw % nb;
  const int m0  = by << 8, n0 = bx << 8;

  const int wm = (wave >> 2) * 128;   // wave M offset within 256
  const int wn = (wave & 3) * 64;     // wave N offset within 256

  fx4 acc[8][4];
#pragma unroll
  for (int i = 0; i < 8; ++i)
#pragma unroll
    for (int j = 0; j < 4; ++j) acc[i][j] = (fx4){0.f, 0.f, 0.f, 0.f};

  // ---- gld16 staging rounds: round = 8KB = 128 rows x 64B across 8 waves --
  const int r_row = wave * 16 + (lane >> 2);        // row within region-half
  const int r_g   = (lane & 3) ^ ((lane >> 3) & 3); // logical granule (swz)
  const f16* gsrc[NGLD];
  int gdst[NGLD];
  {
    int nr = 0;
    auto AR = [&](const f16* P, int mn, int reg, int rb) {
      gsrc[nr] = P + (size_t)(mn + rb + r_row) * K + r_g * 8;
      gdst[nr] = reg * 8192 + rb * 32 + wave * 512;
      ++nr;
    };
    if constexpr (TERMS == 3) {
      if constexpr (!ACONV) {
        AR((const f16*)Ahi_, m0, 0, 0); AR((const f16*)Ahi_, m0, 0, 128);
        AR((const f16*)Alo_, m0, 1, 0); AR((const f16*)Alo_, m0, 1, 128);
      }
      AR(Bhi, n0, 2, 0); AR(Bhi, n0, 2, 128);
      AR(Blo, n0, 3, 0); AR(Blo, n0, 3, 128);
    } else {
      if constexpr (!ACONV) {
        AR((const f16*)Ahi_, m0, 0, 0); AR((const f16*)Ahi_, m0, 0, 128);
      }
      AR(Bhi, n0, 1, 0); AR(Bhi, n0, 1, 128);
    }
  }

  // ---- ACONV: fp32 A prefetched to regs, split hi/lo at ds_write ----------
  const float* A32 = (const float*)Ahi_;
  const float* psrc[4];
  int pdst[4];
  if constexpr (ACONV) {
#pragma unroll
    for (int p = 0; p < 4; ++p) {
      const int e4 = tid + p * 512;            // float4 index in 256x32 tile
      const int arow = e4 >> 3;
      psrc[p] = A32 + (size_t)(m0 + arow) * K + (e4 & 7) * 4;
      const int phys = ((e4 >> 1) & 3) ^ ((e4 >> 4) & 3);  // g ^ ((row>>1)&3)
      pdst[p] = arow * 32 + phys * 8 + (e4 & 1) * 4;
    }
  }

  // ---- prologue: stage tile 0 into buf 0 ----------------------------------
  float4 pf[4];
  if constexpr (ACONV) {
#pragma unroll
    for (int p = 0; p < 4; ++p) pf[p] = *(const float4*)psrc[p];
  }
#pragma unroll
  for (int r = 0; r < NGLD; ++r) gld16(gsrc[r], lds + gdst[r]);

  const int KT  = K >> 5;
  const int pg8 = ((lane >> 4) ^ ((lr >> 1) & 3)) * 8;  // read-side swizzle

  for (int t = 0; t < KT; ++t) {
    f16* const sb  = lds + (t & 1) * BS;
    f16* const nsb = lds + ((t + 1) & 1) * BS;
    const int ktn = (t + 1 < KT ? t + 1 : t) * 32;   // phantom clamp (no peel)

    // (a) ACONV: write current tile's A (compiler waits pf's vmem deps)
    if constexpr (ACONV) {
#pragma unroll
      for (int p = 0; p < 4; ++p) {
        const float4 v = pf[p];
        h4 hh; hh.x = (f16)v.x; hh.y = (f16)v.y; hh.z = (f16)v.z; hh.w = (f16)v.w;
        *(h4*)(sb + pdst[p]) = hh;
        if constexpr (TERMS == 3) {
          h4 ll;
          ll.x = (f16)(v.x - (float)hh.x); ll.y = (f16)(v.y - (float)hh.y);
          ll.z = (f16)(v.z - (float)hh.z); ll.w = (f16)(v.w - (float)hh.w);
          *(h4*)(sb + 8192 + pdst[p]) = ll;
        }
      }
      asm volatile("s_waitcnt lgkmcnt(0)" ::: "memory");
    }
    // (b) issue next tile's staging (deep prefetch; stays in flight)
    if constexpr (ACONV) {
#pragma unroll
      for (int p = 0; p < 4; ++p) pf[p] = *(const float4*)(psrc[p] + ktn);
    }
#pragma unroll
    for (int r = 0; r < NGLD; ++r) gld16(gsrc[r] + ktn, nsb + gdst[r]);
    // (c) counted wait: current tile's gld16 done, next tile's still in flight
    if constexpr (!ACONV) waitvm<NGLD>();
    // (d) all waves staged
    __builtin_amdgcn_s_barrier();
    asm volatile("" ::: "memory");

    // (e) compute phases
    const f16* sAh = sb;
    const f16* sAl = sb + 8192;
    const f16* sBh = sb + (TERMS == 3 ? 2 : 1) * 8192;
    const f16* sBl = sb + 3 * 8192;

    h8 vbh[4], vbl[4];
#pragma unroll
    for (int j = 0; j < 4; ++j) {
      const int row = wn + j * 16 + lr;
      vbh[j] = *(const h8*)(sBh + row * 32 + pg8);
      if constexpr (TERMS == 3) vbl[j] = *(const h8*)(sBl + row * 32 + pg8);
    }
#pragma unroll
    for (int mq = 0; mq < 2; ++mq) {
      h8 va[4];
#pragma unroll
      for (int i = 0; i < 4; ++i)
        va[i] = *(const h8*)(sAh + (wm + mq * 64 + i * 16 + lr) * 32 + pg8);
      __builtin_amdgcn_s_setprio(1);
#pragma unroll
      for (int i = 0; i < 4; ++i)
#pragma unroll
        for (int j = 0; j < 4; ++j) {
          acc[mq * 4 + i][j] = __builtin_amdgcn_mfma_f32_16x16x32_f16(
              va[i], vbh[j], acc[mq * 4 + i][j], 0, 0, 0);
          if constexpr (TERMS == 3)
            acc[mq * 4 + i][j] = __builtin_amdgcn_mfma_f32_16x16x32_f16(
                va[i], vbl[j], acc[mq * 4 + i][j], 0, 0, 0);
        }
      __builtin_amdgcn_s_setprio(0);
      if constexpr (TERMS == 3) {
        h8 vl[4];
#pragma unroll
        for (int i = 0; i < 4; ++i)
          vl[i] = *(const h8*)(sAl + (wm + mq * 64 + i * 16 + lr) * 32 + pg8);
        __builtin_amdgcn_s_setprio(1);
#pragma unroll
        for (int i = 0; i < 4; ++i)
#pragma unroll
          for (int j = 0; j < 4; ++j)
            acc[mq * 4 + i][j] = __builtin_amdgcn_mfma_f32_16x16x32_f16(
                vl[i], vbh[j], acc[mq * 4 + i][j], 0, 0, 0);
        __builtin_amdgcn_s_setprio(0);
      }
    }
    // protect buffers: all reads done before next iter's writes
    __builtin_amdgcn_s_barrier();
    asm volatile("" ::: "memory");
  }

  // ---- epilogue: D[(lane>>4)*4+q][lane&15] per 16x16 fragment -------------
  const int rq = (lane >> 4) * 4;
#pragma unroll
  for (int mi = 0; mi < 8; ++mi) {
#pragma unroll
    for (int q = 0; q < 4; ++q) {
      const int row = m0 + wm + mi * 16 + rq + q;
      const float* gr = nullptr;
      if constexpr (GATHER) gr = growp + (size_t)gidx[row] * gldw;
#pragma unroll
      for (int j = 0; j < 4; ++j) {
        const int col = n0 + wn + j * 16 + lr;
        float v = acc[mi][j][q];
        if (bias) v += bias[col];
        if constexpr (GATHER) v += gr[col];
        if constexpr (RELU) v = fmaxf(v, 0.f);
        const f16 hh = (f16)v;
        Chi[(size_t)row * N + col] = hh;
        if constexpr (WLO) Clo[(size_t)row * N + col] = (f16)(v - (float)hh);
      }
    }
  }
}

// ============== 128x128 MFMA GEMM (kept for wo3-P and wd1) =================
template <int TERMS, int RELU, int GATHER, int WLO, int ACONV>
__global__ __launch_bounds__(256, 2) void gemm128(
    const void* __restrict__ Ahi_, const void* __restrict__ Alo_,
    const f16* __restrict__ Bhi, const f16* __restrict__ Blo,
    const float* __restrict__ bias,
    f16* __restrict__ Chi, f16* __restrict__ Clo,
    int M, int N, int K,
    const int* __restrict__ gidx, const float* __restrict__ growp, int gldw) {
  constexpr int NTILE = (TERMS == 3) ? 4 : 2;
  __shared__ f16 lds[NTILE * 4096];
  f16* sAh = lds;
  f16* sBh = lds + 4096;

  const int tid  = threadIdx.x;
  const int wave = tid >> 6;
  const int lane = tid & 63;
  const int n0 = blockIdx.x * 128;
  const int m0 = blockIdx.y * 128;
  const int wm = (wave >> 1) * 64;
  const int wn = (wave & 1) * 64;
  const int lr = lane & 15;
  const int lk = (lane >> 4) * 8;

  fx4 acc[4][4];
#pragma unroll
  for (int i = 0; i < 4; ++i)
#pragma unroll
    for (int j = 0; j < 4; ++j) acc[i][j] = (fx4){0.f, 0.f, 0.f, 0.f};

  const int sb = wave * 2048 + (lane << 4);

  for (int kt = 0; kt < K; kt += 32) {
#pragma unroll
    for (int c = 0; c < 2; ++c) {
      const int boff = sb + c * 1024;
      const int row  = boff >> 6;
      const int col  = (boff & 63) >> 1;
      gld16(Bhi + (size_t)(n0 + row) * K + kt + col, sBh + (wave * 2 + c) * 512);
      gld16(((const f16*)Ahi_) + (size_t)(m0 + row) * K + kt + col,
            sAh + (wave * 2 + c) * 512);
    }
    __syncthreads();

    h8 ah[4], bh[4];
#pragma unroll
    for (int t = 0; t < 4; ++t) {
      ah[t] = *(const h8*)&sAh[(wm + t * 16 + lr) * 32 + lk];
      bh[t] = *(const h8*)&sBh[(wn + t * 16 + lr) * 32 + lk];
    }
#pragma unroll
    for (int i = 0; i < 4; ++i)
#pragma unroll
      for (int j = 0; j < 4; ++j)
        acc[i][j] = __builtin_amdgcn_mfma_f32_16x16x32_f16(ah[i], bh[j], acc[i][j], 0, 0, 0);
    __syncthreads();
  }

  const int rq = (lane >> 4) * 4;
#pragma unroll
  for (int i = 0; i < 4; ++i) {
#pragma unroll
    for (int q = 0; q < 4; ++q) {
      const int row = m0 + wm + i * 16 + rq + q;
#pragma unroll
      for (int j = 0; j < 4; ++j) {
        const int col = n0 + wn + j * 16 + lr;
        float v = acc[i][j][q];
        if (bias) v += bias[col];
        if constexpr (RELU) v = fmaxf(v, 0.f);
        Chi[(size_t)row * N + col] = (f16)v;
      }
    }
  }
}

// ====== weight transpose+convert: (K,N) fp32 -> (Npad,K) f16 hi[/lo] =======
template <int SPLIT>
__global__ __launch_bounds__(256) void wtransT(
    const float* __restrict__ src, f16* __restrict__ hi, f16* __restrict__ lo,
    int K, int N, int Npad) {
  __shared__ float t[32][33];
  const int bn = blockIdx.x * 32;
  const int bk = blockIdx.y * 32;
  const int tx = threadIdx.x & 31, ty = threadIdx.x >> 5;
#pragma unroll
  for (int r = ty; r < 32; r += 8) {
    const float v = (bn + tx < N) ? src[(size_t)(bk + r) * N + bn + tx] : 0.f;
    t[tx][r] = v;
  }
  __syncthreads();
#pragma unroll
  for (int r = ty; r < 32; r += 8) {
    const float v = t[r][tx];
    const f16 hh = (f16)v;
    hi[(size_t)(bn + r) * K + bk + tx] = hh;
    if (SPLIT) lo[(size_t)(bn + r) * K + bk + tx] = (f16)(v - (float)hh);
  }
}

// ====== skinny logits: (M,16) = (hi+lo)(M,2048) @ W(2048,16) + b ============
__global__ __launch_bounds__(256) void skinny16_hl(
    const f16* __restrict__ Ahi, const f16* __restrict__ Alo,
    const float* __restrict__ W, const float* __restrict__ bias,
    float* __restrict__ out) {
  __shared__ float row[H_];
  __shared__ float red[256];
  const int m = blockIdx.x;
  const f16* ah = Ahi + (size_t)m * H_;
  const f16* al = Alo + (size_t)m * H_;
  for (int i = threadIdx.x; i < H_ / 4; i += 256) {
    const h4 hh = ((const h4*)ah)[i];
    const h4 ll = ((const h4*)al)[i];
    row[i * 4 + 0] = (float)hh.x + (float)ll.x;
    row[i * 4 + 1] = (float)hh.y + (float)ll.y;
    row[i * 4 + 2] = (float)hh.z + (float)ll.z;
    row[i * 4 + 3] = (float)hh.w + (float)ll.w;
  }
  __syncthreads();
  const int c = threadIdx.x & 15, seg = threadIdx.x >> 4;
  const int k0 = seg * (H_ / 16);
  float p = 0.f;
  for (int i = 0; i < H_ / 16; ++i)
    p = fmaf(row[k0 + i], W[(size_t)(k0 + i) * C_ + c], p);
  red[threadIdx.x] = p;
  __syncthreads();
  if (threadIdx.x < C_) {
    float s = bias[threadIdx.x];
    for (int sg = 0; sg < 16; ++sg) s += red[sg * 16 + threadIdx.x];
    out[(size_t)m * C_ + threadIdx.x] = s;
  }
}

// ---------------- JAX categorical: argmax(logits + gumbel) -----------------
__global__ void sample_kernel(const float* __restrict__ logits,
                              int* __restrict__ s_out,
                              float* __restrict__ centers_out,
                              uint32_t ka, uint32_t kb, int which) {
  const int m = blockIdx.x * blockDim.x + threadIdx.x;
  if (m >= NT_) return;
  float best = -3.4e38f;
  int bi = 0;
#pragma unroll
  for (int c = 0; c < C_; ++c) {
    const uint32_t j = (uint32_t)(m * C_ + c);
    uint32_t o0, o1;
    tf2x32(ka, kb, 0u, j, o0, o1);
    const uint32_t bits = o0 ^ o1;
    const uint32_t fb = (bits >> 9) | 0x3f800000u;
    float u = __uint_as_float(fb) - 1.0f;
    u = fmaxf(1.17549435e-38f, u);
    const float gmb = -logf(-logf(u));
    const float z = gmb + logits[(size_t)m * C_ + c];
    if (z > best) { best = z; bi = c; }
  }
  s_out[m] = bi;
  centers_out[(size_t)m * G_ + which] = (float)bi;
}

// ---------------- dec_in gather: codebook rows -> f16 ----------------------
__global__ void gather_dec_kernel(const float* __restrict__ codebook,
                                  const int* __restrict__ s1,
                                  const int* __restrict__ s2,
                                  f16* __restrict__ dec_in) {
  const int idx = blockIdx.x * blockDim.x + threadIdx.x;
  const int m = idx >> 9, d = idx & 511;
  const int g = d >> 8, dd = d & 255;
  const int s = g ? s2[m] : s1[m];
  dec_in[idx] = (f16)codebook[(size_t)(g * C_ + s) * D_ + dd];
}

// ------- final: decoded = dec_h@wd2+bd2 ; pred = decoded + P gather --------
__global__ __launch_bounds__(320) void final2(
    const f16* __restrict__ P,
    const float* __restrict__ bo3,
    const f16* __restrict__ dech,
    const float* __restrict__ wd2, const float* __restrict__ bd2,
    const int* __restrict__ s1, const int* __restrict__ s2,
    float* __restrict__ out_pred, float* __restrict__ out_dec) {
  __shared__ float drow[DECH_];
  const int m = blockIdx.x;
  for (int i = threadIdx.x; i < DECH_; i += 320)
    drow[i] = (float)dech[(size_t)m * DECH_ + i];
  __syncthreads();
  const int a1 = s1[m], a2 = s2[m];
  const int c = threadIdx.x >> 3, g = threadIdx.x & 7;
  float pdec = 0.f;
  if (c < WA_) {
    for (int i = 0; i < DECH_ / 8; ++i) {
      const int k = g * (DECH_ / 8) + i;
      pdec = fmaf(drow[k], wd2[(size_t)k * WA_ + c], pdec);
    }
  }
#pragma unroll
  for (int off = 1; off < 8; off <<= 1) pdec += __shfl_xor(pdec, off);
  if (c < WA_ && g == 0) {
    const float dec = pdec + bd2[c];
    const float soff = (float)P[(size_t)m * NPAD_ + a1 * WA_ + c]
                     + (float)P[(size_t)m * NPAD_ + C_ * WA_ + a2 * WA_ + c]
                     + bo3[a1 * WA_ + c] + bo3[C_ * WA_ + a2 * WA_ + c];
    out_dec[(size_t)m * WA_ + c] = dec;
    out_pred[(size_t)m * WA_ + c] = dec + soff;
  }
}

// ---------------------------------------------------------------------------
extern "C" void kernel_launch(void* const* d_in, const int* in_sizes, int n_in,
                              void* d_out, int out_size, void* d_ws, size_t ws_size,
                              hipStream_t stream) {
  const float* x    = (const float*)d_in[0];
  const float* w11  = (const float*)d_in[1];
  const float* b11  = (const float*)d_in[2];
  const float* w12  = (const float*)d_in[3];
  const float* b12  = (const float*)d_in[4];
  const float* w13  = (const float*)d_in[5];
  const float* b13  = (const float*)d_in[6];
  const float* w21  = (const float*)d_in[7];
  const float* b21  = (const float*)d_in[8];
  const float* w22  = (const float*)d_in[9];
  const float* b22  = (const float*)d_in[10];
  const float* wo1  = (const float*)d_in[11];
  const float* bo1  = (const float*)d_in[12];
  const float* wo2  = (const float*)d_in[13];
  const float* bo2  = (const float*)d_in[14];
  const float* wo3  = (const float*)d_in[15];
  const float* bo3  = (const float*)d_in[16];
  const float* cbk  = (const float*)d_in[17];
  const float* wd1  = (const float*)d_in[18];
  const float* bd1  = (const float*)d_in[19];
  const float* wd2  = (const float*)d_in[20];
  const float* bd2  = (const float*)d_in[21];

  float* out = (float*)d_out;
  float* out_pred = out;
  float* out_dec  = out + (size_t)NT_ * WA_;
  float* out_l1   = out + (size_t)2 * NT_ * WA_;
  float* out_l2   = out_l1 + (size_t)NT_ * C_;
  float* out_sc   = out_l2 + (size_t)NT_ * C_;

  // workspace layout (144 MB footprint, same as round 2):
  const size_t AB = (size_t)NT_ * H_;
  f16* R0a = (f16*)d_ws;                 // h1-hi | o1 | dec_in/dec_h
  f16* R0b = R0a + AB;                   // h1-lo | o2
  f16* R1a = R0b + AB;                   // h-hi, h2-hi | P (NT x 1152)
  f16* R1b = R1a + AB;                   // h-lo, h2-lo
  f16* WH  = R1b + AB;                   // 2048x2048 f16
  f16* WL  = WH + (size_t)H_ * H_;
  int* S1  = (int*)(WL + (size_t)H_ * H_);
  int* S2  = S1 + NT_;

  f16* P     = R1a;
  f16* DECIN = R0a;
  f16* DECH  = R0a + (size_t)NT_ * DECH_;

  // raise dynamic-LDS limits for the 256^2 kernels
  hipFuncSetAttribute(reinterpret_cast<const void*>(&gemm256<3,1,0,1,1>),
                      hipFuncAttributeMaxDynamicSharedMemorySize, 131072);
  hipFuncSetAttribute(reinterpret_cast<const void*>(&gemm256<3,1,0,1,0>),
                      hipFuncAttributeMaxDynamicSharedMemorySize, 131072);
  hipFuncSetAttribute(reinterpret_cast<const void*>(&gemm256<3,1,1,1,1>),
                      hipFuncAttributeMaxDynamicSharedMemorySize, 131072);
  hipFuncSetAttribute(reinterpret_cast<const void*>(&gemm256<1,1,0,0,1>),
                      hipFuncAttributeMaxDynamicSharedMemorySize, 65536);
  hipFuncSetAttribute(reinterpret_cast<const void*>(&gemm256<1,1,0,0,0>),
                      hipFuncAttributeMaxDynamicSharedMemorySize, 65536);

  // subkeys of jax.random.split(jax.random.key(42)); key data = [0,42]
  uint32_t k1a, k1b, k2a, k2b;
  tf2x32(0u, 42u, 0u, 0u, k1a, k1b);
  tf2x32(0u, 42u, 0u, 1u, k2a, k2b);

  const dim3 b256(256), b512(512);
  const dim3 gW(H_ / 32, H_ / 32);
  const dim3 gWo3(NPAD_ / 32, H_ / 32);
  const dim3 gWd1(DECH_ / 32, DECH_ / 32);
  const dim3 gBig((NT_ / 256) * (H_ / 256));      // 256 blocks, 1 per CU
  const dim3 gP(NPAD_ / 128, NT_ / 128);
  const dim3 gD(DECH_ / 128, NT_ / 128);

  // ---- bin1: h1 = relu(x@w11+b11); h = relu(h1@w12+b12); l1 = h@w13+b13
  wtransT<1><<<gW, b256, 0, stream>>>(w11, WH, WL, H_, H_, H_);
  gemm256<3,1,0,1,1><<<gBig, b512, 131072, stream>>>(
      x, nullptr, WH, WL, b11, R0a, R0b, NT_, H_, DIN_, nullptr, nullptr, 0);
  wtransT<1><<<gW, b256, 0, stream>>>(w12, WH, WL, H_, H_, H_);
  gemm256<3,1,0,1,0><<<gBig, b512, 131072, stream>>>(
      R0a, R0b, WH, WL, b12, R1a, R1b, NT_, H_, H_, nullptr, nullptr, 0);
  skinny16_hl<<<NT_, 256, 0, stream>>>(R1a, R1b, w13, b13, out_l1);
  sample_kernel<<<NT_ / 256, 256, 0, stream>>>(out_l1, S1, out_sc, k1a, k1b, 0);

  // ---- bin2: h2 = relu(x@w21[:2048] + w21[2048+s1] + b21); l2 = h2@w22+b22
  wtransT<1><<<gW, b256, 0, stream>>>(w21, WH, WL, H_, H_, H_);
  gemm256<3,1,1,1,1><<<gBig, b512, 131072, stream>>>(
      x, nullptr, WH, WL, b21, R1a, R1b, NT_, H_, DIN_,
      S1, w21 + (size_t)DIN_ * H_, H_);
  skinny16_hl<<<NT_, 256, 0, stream>>>(R1a, R1b, w22, b22, out_l2);
  sample_kernel<<<NT_ / 256, 256, 0, stream>>>(out_l2, S2, out_sc, k2a, k2b, 1);

  // ---- offsets: o1 = relu(x@wo1+bo1); o2 = relu(o1@wo2+bo2); P = o2@wo3
  wtransT<0><<<gW, b256, 0, stream>>>(wo1, WH, nullptr, H_, H_, H_);
  gemm256<1,1,0,0,1><<<gBig, b512, 65536, stream>>>(
      x, nullptr, WH, nullptr, bo1, R0a, nullptr, NT_, H_, DIN_, nullptr, nullptr, 0);
  wtransT<0><<<gW, b256, 0, stream>>>(wo2, WH, nullptr, H_, H_, H_);
  gemm256<1,1,0,0,0><<<gBig, b512, 65536, stream>>>(
      R0a, nullptr, WH, nullptr, bo2, R0b, nullptr, NT_, H_, H_, nullptr, nullptr, 0);
  wtransT<0><<<gWo3, b256, 0, stream>>>(wo3, WH, nullptr, H_, G_ * C_ * WA_, NPAD_);
  gemm128<1,0,0,0,0><<<gP, b256, 0, stream>>>(
      R0b, nullptr, WH, nullptr, nullptr, P, nullptr, NT_, NPAD_, H_, nullptr, nullptr, 0);

  // ---- decoder: dec_h = relu(dec_in@wd1+bd1)
  gather_dec_kernel<<<(NT_ * DECH_) / 256, 256, 0, stream>>>(cbk, S1, S2, DECIN);
  wtransT<0><<<gWd1, b256, 0, stream>>>(wd1, WH, nullptr, DECH_, DECH_, DECH_);
  gemm128<1,1,0,0,0><<<gD, b256, 0, stream>>>(
      DECIN, nullptr, WH, nullptr, bd1, DECH, nullptr, NT_, DECH_, DECH_, nullptr, nullptr, 0);

  // ---- final combine
  final2<<<NT_, 320, 0, stream>>>(P, bo3, DECH, wd2, bd2, S1, S2, out_pred, out_dec);

  (void)in_sizes; (void)n_in; (void)out_size; (void)ws_size;
}

// Round 4
// 1063.873 us; speedup vs baseline: 5.1779x; 1.0356x over previous
//
#include <hip/hip_runtime.h>
#include <cstdint>
#include <cstddef>

// Problem dims (fixed by reference)
#define NT_   8192
#define DIN_  2048
#define H_    2048
#define C_    16
#define G_    2
#define D_    256
#define WA_   35
#define DECH_ 512
#define NPAD_ 1152   // 1120 padded to 9*128

typedef _Float16 f16;
typedef _Float16 h4 __attribute__((ext_vector_type(4)));
typedef _Float16 h8 __attribute__((ext_vector_type(8)));
typedef float fx4 __attribute__((ext_vector_type(4)));

typedef __attribute__((address_space(1))) const void gvoid_t;
typedef __attribute__((address_space(3))) void lvoid_t;

// async global->LDS, 16B per lane; LDS dest = wave-uniform base + lane*16
__device__ __forceinline__ void gld16(const void* g, void* l) {
  __builtin_amdgcn_global_load_lds((gvoid_t*)(uintptr_t)g,
                                   (lvoid_t*)(uint32_t)(uintptr_t)l, 16, 0, 0);
}

__device__ __forceinline__ void barrier_() {
  asm volatile("" ::: "memory");
  __builtin_amdgcn_s_barrier();
  asm volatile("" ::: "memory");
}

#define MFMA_(d, a, b) d = __builtin_amdgcn_mfma_f32_16x16x32_f16(a, b, d, 0, 0, 0)

// ---------------- threefry2x32 (Random123 / JAX-compatible) ----------------
__host__ __device__ inline void tf2x32(uint32_t k0, uint32_t k1,
                                       uint32_t x0, uint32_t x1,
                                       uint32_t& o0, uint32_t& o1) {
  const uint32_t ks2 = k0 ^ k1 ^ 0x1BD11BDAu;
  uint32_t ks[3] = {k0, k1, ks2};
  x0 += ks[0]; x1 += ks[1];
  const uint32_t R0[4] = {13u, 15u, 26u, 6u};
  const uint32_t R1[4] = {17u, 29u, 16u, 24u};
#pragma unroll
  for (int g = 0; g < 5; ++g) {
    const uint32_t* R = (g & 1) ? R1 : R0;
#pragma unroll
    for (int r = 0; r < 4; ++r) {
      x0 += x1;
      x1 = (x1 << R[r]) | (x1 >> (32u - R[r]));
      x1 ^= x0;
    }
    x0 += ks[(g + 1) % 3];
    x1 += ks[(g + 2) % 3] + (uint32_t)(g + 1);
  }
  o0 = x0; o1 = x1;
}

// ---------------- x split: fp32 -> f16 hi/lo --------------------------------
__global__ __launch_bounds__(256) void xsplit_kernel(
    const float* __restrict__ x, f16* __restrict__ xh, f16* __restrict__ xl) {
  const size_t i = (size_t)blockIdx.x * 256 + threadIdx.x;  // per 8 floats
  const float4 v0 = *(const float4*)(x + i * 8);
  const float4 v1 = *(const float4*)(x + i * 8 + 4);
  float vv[8] = {v0.x, v0.y, v0.z, v0.w, v1.x, v1.y, v1.z, v1.w};
  h8 hh, ll;
#pragma unroll
  for (int k = 0; k < 8; ++k) {
    const f16 h = (f16)vv[k];
    hh[k] = h;
    ll[k] = (f16)(vv[k] - (float)h);
  }
  *(h8*)(xh + i * 8) = hh;
  *(h8*)(xl + i * 8) = ll;
}

// ============ 256x256-tile MFMA GEMM, BK=32, 8 waves, phased schedule =======
// A: (M,K) f16 hi[/lo]; B: (N,K) f16 hi[/lo] (pre-transposed weights)
// EPI_PAIR: C=relu(A@B^T+bias) -> Chi,Clo   EPI_HI: -> Chi only
// EPI_LOGIT: h=relu(A@B^T+bias[+gatherrow]); emit per-k-slice partial logits
//            part[sidx][m][0..15] = sum_k h[m][k]*wlog[k][c]  (sidx = bx*4+wn)
enum { EPI_PAIR = 0, EPI_HI = 1, EPI_LOGIT = 2 };

template <int TERMS, int GATHER, int EPI>
__global__ __launch_bounds__(512, 2) void gemm256(
    const f16* __restrict__ Ah, const f16* __restrict__ Al,
    const f16* __restrict__ Bh, const f16* __restrict__ Bl,
    const float* __restrict__ bias,
    f16* __restrict__ Chi, f16* __restrict__ Clo,
    int M, int N, int K,
    const int* __restrict__ gidx, const float* __restrict__ growp, int gldw,
    const float* __restrict__ wlog, float* __restrict__ part) {
  extern __shared__ f16 lds[];
  constexpr int BS = ((TERMS == 3) ? 4 : 2) * 8192;  // f16 per buffer
  constexpr int NGLD = (TERMS == 3) ? 8 : 4;

  const int tid  = threadIdx.x;
  const int wave = tid >> 6;
  const int lane = tid & 63;
  const int lr   = lane & 15;

  // bijective XCD swizzle (nwg % 8 == 0)
  const int nb  = N >> 8;
  const int nwg = (int)gridDim.x;
  const int qq  = nwg >> 3;
  const int sw  = ((int)blockIdx.x & 7) * qq + ((int)blockIdx.x >> 3);
  const int by  = sw / nb, bx = sw % nb;
  const int m0  = by << 8, n0 = bx << 8;

  const int wm = (wave >> 2) * 128;
  const int wn = (wave & 3) * 64;

  fx4 acc[8][4];
#pragma unroll
  for (int i = 0; i < 8; ++i)
#pragma unroll
    for (int j = 0; j < 4; ++j) acc[i][j] = (fx4){0.f, 0.f, 0.f, 0.f};

  // staging rounds: one round = 512 lanes x 16B = 8KB = 128 rows x 64B
  const int r_row = wave * 16 + (lane >> 2);
  const int r_g   = (lane & 3) ^ ((lane >> 3) & 3);  // src granule (swizzle)
  const f16* gsrc[NGLD];
  int gdst[NGLD];
  {
    int nr = 0;
    auto AR = [&](const f16* P, int mn, int reg, int rb) {
      gsrc[nr] = P + (size_t)(mn + rb + r_row) * K + r_g * 8;
      gdst[nr] = reg * 8192 + rb * 32 + wave * 512;
      ++nr;
    };
    if constexpr (TERMS == 3) {
      AR(Ah, m0, 0, 0); AR(Ah, m0, 0, 128);
      AR(Al, m0, 1, 0); AR(Al, m0, 1, 128);
      AR(Bh, n0, 2, 0); AR(Bh, n0, 2, 128);
      AR(Bl, n0, 3, 0); AR(Bl, n0, 3, 128);
    } else {
      AR(Ah, m0, 0, 0); AR(Ah, m0, 0, 128);
      AR(Bh, n0, 1, 0); AR(Bh, n0, 1, 128);
    }
  }

  // prologue: stage tile 0 into buf0
#pragma unroll
  for (int r = 0; r < NGLD; ++r) gld16(gsrc[r], lds + gdst[r]);
  asm volatile("s_waitcnt vmcnt(0)" ::: "memory");
  barrier_();

  const int pg8 = ((lane >> 4) ^ ((lr >> 1) & 3)) * 8;  // read-side swizzle
  const int KT  = K >> 5;

  for (int t = 0; t < KT; ++t) {
    f16* const sb  = lds + (t & 1) * BS;
    f16* const nsb = lds + ((t + 1) & 1) * BS;
    const int ktn = (t + 1 < KT ? t + 1 : t) * 32;  // phantom tail reload

    const f16* sAh = sb;
    const f16* sAl = sb + 8192;
    const f16* sBh = sb + (TERMS == 3 ? 2 : 1) * 8192;
    const f16* sBl = sb + 3 * 8192;

    h8 vbh[4], vbl[4], va[4];
    // ---------------- phase 0: B + A-hi(lower half) -------------------------
#pragma unroll
    for (int j = 0; j < 4; ++j) {
      vbh[j] = *(const h8*)(sBh + (wn + j * 16 + lr) * 32 + pg8);
      if constexpr (TERMS == 3)
        vbl[j] = *(const h8*)(sBl + (wn + j * 16 + lr) * 32 + pg8);
    }
#pragma unroll
    for (int i = 0; i < 4; ++i)
      va[i] = *(const h8*)(sAh + (wm + i * 16 + lr) * 32 + pg8);
    gld16(gsrc[0] + ktn, nsb + gdst[0]);
    gld16(gsrc[1] + ktn, nsb + gdst[1]);
    if constexpr (TERMS == 3) gld16(gsrc[2] + ktn, nsb + gdst[2]);
    barrier_();
    asm volatile("s_waitcnt lgkmcnt(0)" ::: "memory");
    __builtin_amdgcn_sched_barrier(0);
    __builtin_amdgcn_s_setprio(1);
#pragma unroll
    for (int i = 0; i < 4; ++i)
#pragma unroll
      for (int j = 0; j < 4; ++j) MFMA_(acc[i][j], va[i], vbh[j]);
    if constexpr (TERMS == 3) {
#pragma unroll
      for (int i = 0; i < 4; ++i)
#pragma unroll
        for (int j = 0; j < 4; ++j) MFMA_(acc[i][j], va[i], vbl[j]);
    }
    __builtin_amdgcn_s_setprio(0);
    barrier_();
    // ---------------- phase 1: A-hi(upper half) -----------------------------
#pragma unroll
    for (int i = 0; i < 4; ++i)
      va[i] = *(const h8*)(sAh + (wm + 64 + i * 16 + lr) * 32 + pg8);
    if constexpr (TERMS == 3) {
      gld16(gsrc[3] + ktn, nsb + gdst[3]);
      gld16(gsrc[4] + ktn, nsb + gdst[4]);
      gld16(gsrc[5] + ktn, nsb + gdst[5]);
    } else {
      gld16(gsrc[2] + ktn, nsb + gdst[2]);
      gld16(gsrc[3] + ktn, nsb + gdst[3]);
    }
    barrier_();
    asm volatile("s_waitcnt lgkmcnt(0)" ::: "memory");
    __builtin_amdgcn_sched_barrier(0);
    __builtin_amdgcn_s_setprio(1);
#pragma unroll
    for (int i = 0; i < 4; ++i)
#pragma unroll
      for (int j = 0; j < 4; ++j) MFMA_(acc[4 + i][j], va[i], vbh[j]);
    if constexpr (TERMS == 3) {
#pragma unroll
      for (int i = 0; i < 4; ++i)
#pragma unroll
        for (int j = 0; j < 4; ++j) MFMA_(acc[4 + i][j], va[i], vbl[j]);
    }
    __builtin_amdgcn_s_setprio(0);
    if constexpr (TERMS != 3) asm volatile("s_waitcnt vmcnt(0)" ::: "memory");
    barrier_();
    // ---------------- phase 2 (3-term only): A-lo x B-hi --------------------
    if constexpr (TERMS == 3) {
      h8 vl0[4], vl1[4];
#pragma unroll
      for (int i = 0; i < 4; ++i) {
        vl0[i] = *(const h8*)(sAl + (wm + i * 16 + lr) * 32 + pg8);
        vl1[i] = *(const h8*)(sAl + (wm + 64 + i * 16 + lr) * 32 + pg8);
      }
      gld16(gsrc[6] + ktn, nsb + gdst[6]);
      gld16(gsrc[7] + ktn, nsb + gdst[7]);
      barrier_();
      asm volatile("s_waitcnt lgkmcnt(0)" ::: "memory");
      __builtin_amdgcn_sched_barrier(0);
      __builtin_amdgcn_s_setprio(1);
#pragma unroll
      for (int i = 0; i < 4; ++i)
#pragma unroll
        for (int j = 0; j < 4; ++j) {
          MFMA_(acc[i][j], vl0[i], vbh[j]);
          MFMA_(acc[4 + i][j], vl1[i], vbh[j]);
        }
      __builtin_amdgcn_s_setprio(0);
      asm volatile("s_waitcnt vmcnt(0)" ::: "memory");
      barrier_();
    }
  }

  // ---- epilogues ----
  const int rq = (lane >> 4) * 4;
  if constexpr (EPI == EPI_LOGIT) {
    // finalize h-tile in place: bias [+gather] + relu
#pragma unroll
    for (int mi = 0; mi < 8; ++mi) {
#pragma unroll
      for (int q = 0; q < 4; ++q) {
        const int row = m0 + wm + mi * 16 + rq + q;
        const float* gr = nullptr;
        if constexpr (GATHER) gr = growp + (size_t)gidx[row] * gldw;
#pragma unroll
        for (int j = 0; j < 4; ++j) {
          const int col = n0 + wn + j * 16 + lr;
          float v = acc[mi][j][q] + bias[col];
          if constexpr (GATHER) v += gr[col];
          acc[mi][j][q] = fmaxf(v, 0.f);
        }
      }
    }
    // in-register logit dot: partial[c] = sum_k h[m][k]*wlog[k][c]
    const int sidx = bx * 4 + (wave & 3);
    float* pout = part + ((size_t)sidx * NT_ + (m0 + wm)) * 16;
    const int qw = lr >> 2, cw = lr & 3;
#pragma unroll
    for (int cc = 0; cc < 4; ++cc) {
      float4 wv[4];
#pragma unroll
      for (int j = 0; j < 4; ++j)
        wv[j] = *(const float4*)(wlog + (size_t)(n0 + wn + j * 16 + lr) * 16 + cc * 4);
#pragma unroll
      for (int mi = 0; mi < 8; ++mi) {
        float pl[4][4] = {{0.f}};
#pragma unroll
        for (int j = 0; j < 4; ++j)
#pragma unroll
          for (int q = 0; q < 4; ++q) {
            pl[q][0] += acc[mi][j][q] * wv[j].x;
            pl[q][1] += acc[mi][j][q] * wv[j].y;
            pl[q][2] += acc[mi][j][q] * wv[j].z;
            pl[q][3] += acc[mi][j][q] * wv[j].w;
          }
        // reduce over the 16 lanes of the lr-group (they hold disjoint k)
#pragma unroll
        for (int st = 1; st < 16; st <<= 1) {
#pragma unroll
          for (int q = 0; q < 4; ++q)
#pragma unroll
            for (int c = 0; c < 4; ++c) pl[q][c] += __shfl_xor(pl[q][c], st);
        }
        pout[(size_t)(mi * 16 + rq + qw) * 16 + cc * 4 + cw] = pl[qw][cw];
      }
    }
  } else {
#pragma unroll
    for (int mi = 0; mi < 8; ++mi) {
#pragma unroll
      for (int q = 0; q < 4; ++q) {
        const int row = m0 + wm + mi * 16 + rq + q;
#pragma unroll
        for (int j = 0; j < 4; ++j) {
          const int col = n0 + wn + j * 16 + lr;
          float v = fmaxf(acc[mi][j][q] + bias[col], 0.f);
          const f16 hh = (f16)v;
          Chi[(size_t)row * N + col] = hh;
          if constexpr (EPI == EPI_PAIR)
            Clo[(size_t)row * N + col] = (f16)(v - (float)hh);
        }
      }
    }
  }
}

// ============== 128x128 MFMA GEMM (kept for wo3-P and wd1) =================
template <int RELU>
__global__ __launch_bounds__(256, 2) void gemm128(
    const f16* __restrict__ Ah, const f16* __restrict__ Bh,
    const float* __restrict__ bias, f16* __restrict__ Chi,
    int M, int N, int K) {
  __shared__ f16 lds[2 * 4096];
  f16* sAh = lds;
  f16* sBh = lds + 4096;

  const int tid  = threadIdx.x;
  const int wave = tid >> 6;
  const int lane = tid & 63;
  const int n0 = blockIdx.x * 128;
  const int m0 = blockIdx.y * 128;
  const int wm = (wave >> 1) * 64;
  const int wn = (wave & 1) * 64;
  const int lr = lane & 15;
  const int lk = (lane >> 4) * 8;

  fx4 acc[4][4];
#pragma unroll
  for (int i = 0; i < 4; ++i)
#pragma unroll
    for (int j = 0; j < 4; ++j) acc[i][j] = (fx4){0.f, 0.f, 0.f, 0.f};

  const int sb = wave * 2048 + (lane << 4);

  for (int kt = 0; kt < K; kt += 32) {
#pragma unroll
    for (int c = 0; c < 2; ++c) {
      const int boff = sb + c * 1024;
      const int row  = boff >> 6;
      const int col  = (boff & 63) >> 1;
      gld16(Bh + (size_t)(n0 + row) * K + kt + col, sBh + (wave * 2 + c) * 512);
      gld16(Ah + (size_t)(m0 + row) * K + kt + col, sAh + (wave * 2 + c) * 512);
    }
    __syncthreads();

    h8 ah[4], bh[4];
#pragma unroll
    for (int t = 0; t < 4; ++t) {
      ah[t] = *(const h8*)&sAh[(wm + t * 16 + lr) * 32 + lk];
      bh[t] = *(const h8*)&sBh[(wn + t * 16 + lr) * 32 + lk];
    }
#pragma unroll
    for (int i = 0; i < 4; ++i)
#pragma unroll
      for (int j = 0; j < 4; ++j) MFMA_(acc[i][j], ah[i], bh[j]);
    __syncthreads();
  }

  const int rq = (lane >> 4) * 4;
#pragma unroll
  for (int i = 0; i < 4; ++i) {
#pragma unroll
    for (int q = 0; q < 4; ++q) {
      const int row = m0 + wm + i * 16 + rq + q;
#pragma unroll
      for (int j = 0; j < 4; ++j) {
        const int col = n0 + wn + j * 16 + lr;
        float v = acc[i][j][q];
        if (bias) v += bias[col];
        if constexpr (RELU) v = fmaxf(v, 0.f);
        Chi[(size_t)row * N + col] = (f16)v;
      }
    }
  }
}

// ====== weight transpose+convert: (K,N) fp32 -> (Npad,K) f16 hi[/lo] =======
template <int SPLIT>
__global__ __launch_bounds__(256) void wtransT(
    const float* __restrict__ src, f16* __restrict__ hi, f16* __restrict__ lo,
    int K, int N, int Npad) {
  __shared__ float t[32][33];
  const int bn = blockIdx.x * 32;
  const int bk = blockIdx.y * 32;
  const int tx = threadIdx.x & 31, ty = threadIdx.x >> 5;
#pragma unroll
  for (int r = ty; r < 32; r += 8) {
    const float v = (bn + tx < N) ? src[(size_t)(bk + r) * N + bn + tx] : 0.f;
    t[tx][r] = v;
  }
  __syncthreads();
#pragma unroll
  for (int r = ty; r < 32; r += 8) {
    const float v = t[r][tx];
    const f16 hh = (f16)v;
    hi[(size_t)(bn + r) * K + bk + tx] = hh;
    if (SPLIT) lo[(size_t)(bn + r) * K + bk + tx] = (f16)(v - (float)hh);
  }
}

// ====== reduce partials + bias -> logits; fused JAX categorical sample =====
__global__ __launch_bounds__(256) void reduce_sample(
    const float* __restrict__ part, const float* __restrict__ bias,
    float* __restrict__ logits_out, int* __restrict__ s_out,
    float* __restrict__ centers_out, uint32_t ka, uint32_t kb, int which) {
  const int tid = threadIdx.x;
  const int c = tid & 15;
  const int m = blockIdx.x * 16 + (tid >> 4);
  float v = bias[c];
#pragma unroll 8
  for (int s = 0; s < 32; ++s) v += part[((size_t)s * NT_ + m) * 16 + c];
  logits_out[(size_t)m * C_ + c] = v;
  // gumbel (JAX threefry bits, partitionable path)
  const uint32_t j = (uint32_t)(m * C_ + c);
  uint32_t o0, o1;
  tf2x32(ka, kb, 0u, j, o0, o1);
  const uint32_t bits = o0 ^ o1;
  float u = __uint_as_float((bits >> 9) | 0x3f800000u) - 1.0f;
  u = fmaxf(1.17549435e-38f, u);
  float z = -logf(-logf(u)) + v;
  int bi = c;
#pragma unroll
  for (int st = 1; st < 16; st <<= 1) {
    const float oz = __shfl_xor(z, st);
    const int   ob = __shfl_xor(bi, st);
    if (oz > z || (oz == z && ob < bi)) { z = oz; bi = ob; }
  }
  if (c == 0) {
    s_out[m] = bi;
    centers_out[(size_t)m * G_ + which] = (float)bi;
  }
}

// ---------------- dec_in gather: codebook rows -> f16 ----------------------
__global__ void gather_dec_kernel(const float* __restrict__ codebook,
                                  const int* __restrict__ s1,
                                  const int* __restrict__ s2,
                                  f16* __restrict__ dec_in) {
  const int idx = blockIdx.x * blockDim.x + threadIdx.x;
  const int m = idx >> 9, d = idx & 511;
  const int g = d >> 8, dd = d & 255;
  const int s = g ? s2[m] : s1[m];
  dec_in[idx] = (f16)codebook[(size_t)(g * C_ + s) * D_ + dd];
}

// ------- final: decoded = dec_h@wd2+bd2 ; pred = decoded + P gather --------
__global__ __launch_bounds__(320) void final2(
    const f16* __restrict__ P,
    const float* __restrict__ bo3,
    const f16* __restrict__ dech,
    const float* __restrict__ wd2, const float* __restrict__ bd2,
    const int* __restrict__ s1, const int* __restrict__ s2,
    float* __restrict__ out_pred, float* __restrict__ out_dec) {
  __shared__ float drow[DECH_];
  const int m = blockIdx.x;
  for (int i = threadIdx.x; i < DECH_; i += 320)
    drow[i] = (float)dech[(size_t)m * DECH_ + i];
  __syncthreads();
  const int a1 = s1[m], a2 = s2[m];
  const int c = threadIdx.x >> 3, g = threadIdx.x & 7;
  float pdec = 0.f;
  if (c < WA_) {
    for (int i = 0; i < DECH_ / 8; ++i) {
      const int k = g * (DECH_ / 8) + i;
      pdec = fmaf(drow[k], wd2[(size_t)k * WA_ + c], pdec);
    }
  }
#pragma unroll
  for (int off = 1; off < 8; off <<= 1) pdec += __shfl_xor(pdec, off);
  if (c < WA_ && g == 0) {
    const float dec = pdec + bd2[c];
    const float soff = (float)P[(size_t)m * NPAD_ + a1 * WA_ + c]
                     + (float)P[(size_t)m * NPAD_ + C_ * WA_ + a2 * WA_ + c]
                     + bo3[a1 * WA_ + c] + bo3[C_ * WA_ + a2 * WA_ + c];
    out_dec[(size_t)m * WA_ + c] = dec;
    out_pred[(size_t)m * WA_ + c] = dec + soff;
  }
}

// ---------------------------------------------------------------------------
extern "C" void kernel_launch(void* const* d_in, const int* in_sizes, int n_in,
                              void* d_out, int out_size, void* d_ws, size_t ws_size,
                              hipStream_t stream) {
  const float* x    = (const float*)d_in[0];
  const float* w11  = (const float*)d_in[1];
  const float* b11  = (const float*)d_in[2];
  const float* w12  = (const float*)d_in[3];
  const float* b12  = (const float*)d_in[4];
  const float* w13  = (const float*)d_in[5];
  const float* b13  = (const float*)d_in[6];
  const float* w21  = (const float*)d_in[7];
  const float* b21  = (const float*)d_in[8];
  const float* w22  = (const float*)d_in[9];
  const float* b22  = (const float*)d_in[10];
  const float* wo1  = (const float*)d_in[11];
  const float* bo1  = (const float*)d_in[12];
  const float* wo2  = (const float*)d_in[13];
  const float* bo2  = (const float*)d_in[14];
  const float* wo3  = (const float*)d_in[15];
  const float* bo3  = (const float*)d_in[16];
  const float* cbk  = (const float*)d_in[17];
  const float* wd1  = (const float*)d_in[18];
  const float* bd1  = (const float*)d_in[19];
  const float* wd2  = (const float*)d_in[20];
  const float* bd2  = (const float*)d_in[21];

  float* out = (float*)d_out;
  float* out_pred = out;
  float* out_dec  = out + (size_t)NT_ * WA_;
  float* out_l1   = out + (size_t)2 * NT_ * WA_;
  float* out_l2   = out_l1 + (size_t)NT_ * C_;
  float* out_sc   = out_l2 + (size_t)NT_ * C_;

  // workspace layout (~168 MB)
  const size_t AB = (size_t)NT_ * H_;
  f16*   Xh   = (f16*)d_ws;                       // (NT,2048) f16
  f16*   Xl   = Xh + AB;
  f16*   H1a  = Xl + AB;                          // h1-hi | o1
  f16*   H1b  = H1a + AB;                         // h1-lo | o2
  f16*   WH   = H1b + AB;                         // (2048,2048) f16
  f16*   WL   = WH + (size_t)H_ * H_;
  float* PART = (float*)(WL + (size_t)H_ * H_);   // (32, NT, 16) fp32
  int*   S1   = (int*)(PART + (size_t)32 * NT_ * C_);
  int*   S2   = S1 + NT_;

  f16* O1    = H1a;
  f16* O2    = H1b;
  f16* P     = Xh;                                // after wo1, Xh is dead
  f16* DECIN = Xl;                                // after w21, Xl is dead
  f16* DECH  = Xl + (size_t)NT_ * DECH_;

  hipFuncSetAttribute(reinterpret_cast<const void*>(&gemm256<3,0,EPI_PAIR>),
                      hipFuncAttributeMaxDynamicSharedMemorySize, 131072);
  hipFuncSetAttribute(reinterpret_cast<const void*>(&gemm256<3,0,EPI_LOGIT>),
                      hipFuncAttributeMaxDynamicSharedMemorySize, 131072);
  hipFuncSetAttribute(reinterpret_cast<const void*>(&gemm256<3,1,EPI_LOGIT>),
                      hipFuncAttributeMaxDynamicSharedMemorySize, 131072);
  hipFuncSetAttribute(reinterpret_cast<const void*>(&gemm256<1,0,EPI_HI>),
                      hipFuncAttributeMaxDynamicSharedMemorySize, 65536);

  // subkeys of jax.random.split(jax.random.key(42)); key data = [0,42]
  uint32_t k1a, k1b, k2a, k2b;
  tf2x32(0u, 42u, 0u, 0u, k1a, k1b);
  tf2x32(0u, 42u, 0u, 1u, k2a, k2b);

  const dim3 b256(256), b512(512);
  const dim3 gW(H_ / 32, H_ / 32);
  const dim3 gWo3(NPAD_ / 32, H_ / 32);
  const dim3 gWd1(DECH_ / 32, DECH_ / 32);
  const dim3 gBig((NT_ / 256) * (H_ / 256));   // 256 blocks
  const dim3 gP(NPAD_ / 128, NT_ / 128);
  const dim3 gD(DECH_ / 128, NT_ / 128);

  // ---- x -> hi/lo split (once; feeds w11, w21, wo1)
  xsplit_kernel<<<NT_ * H_ / (8 * 256), b256, 0, stream>>>(x, Xh, Xl);

  // ---- bin1: h1 = relu(x@w11+b11); logits1 = relu(h1@w12+b12)@w13+b13
  wtransT<1><<<gW, b256, 0, stream>>>(w11, WH, WL, H_, H_, H_);
  gemm256<3,0,EPI_PAIR><<<gBig, b512, 131072, stream>>>(
      Xh, Xl, WH, WL, b11, H1a, H1b, NT_, H_, DIN_,
      nullptr, nullptr, 0, nullptr, nullptr);
  wtransT<1><<<gW, b256, 0, stream>>>(w12, WH, WL, H_, H_, H_);
  gemm256<3,0,EPI_LOGIT><<<gBig, b512, 131072, stream>>>(
      H1a, H1b, WH, WL, b12, nullptr, nullptr, NT_, H_, H_,
      nullptr, nullptr, 0, w13, PART);
  reduce_sample<<<NT_ / 16, b256, 0, stream>>>(PART, b13, out_l1, S1, out_sc,
                                               k1a, k1b, 0);

  // ---- bin2: logits2 = relu(x@w21[:2048] + w21[2048+s1] + b21)@w22+b22
  wtransT<1><<<gW, b256, 0, stream>>>(w21, WH, WL, H_, H_, H_);
  gemm256<3,1,EPI_LOGIT><<<gBig, b512, 131072, stream>>>(
      Xh, Xl, WH, WL, b21, nullptr, nullptr, NT_, H_, DIN_,
      S1, w21 + (size_t)DIN_ * H_, H_, w22, PART);
  reduce_sample<<<NT_ / 16, b256, 0, stream>>>(PART, b22, out_l2, S2, out_sc,
                                               k2a, k2b, 1);

  // ---- offsets: o1 = relu(x@wo1+bo1); o2 = relu(o1@wo2+bo2); P = o2@wo3
  wtransT<0><<<gW, b256, 0, stream>>>(wo1, WH, nullptr, H_, H_, H_);
  gemm256<1,0,EPI_HI><<<gBig, b512, 65536, stream>>>(
      Xh, nullptr, WH, nullptr, bo1, O1, nullptr, NT_, H_, DIN_,
      nullptr, nullptr, 0, nullptr, nullptr);
  wtransT<0><<<gW, b256, 0, stream>>>(wo2, WH, nullptr, H_, H_, H_);
  gemm256<1,0,EPI_HI><<<gBig, b512, 65536, stream>>>(
      O1, nullptr, WH, nullptr, bo2, O2, nullptr, NT_, H_, H_,
      nullptr, nullptr, 0, nullptr, nullptr);
  wtransT<0><<<gWo3, b256, 0, stream>>>(wo3, WH, nullptr, H_, G_ * C_ * WA_, NPAD_);
  gemm128<0><<<gP, b256, 0, stream>>>(O2, WH, nullptr, P, NT_, NPAD_, H_);

  // ---- decoder: dec_h = relu(dec_in@wd1+bd1)
  gather_dec_kernel<<<(NT_ * DECH_) / 256, b256, 0, stream>>>(cbk, S1, S2, DECIN);
  wtransT<0><<<gWd1, b256, 0, stream>>>(wd1, WH, nullptr, DECH_, DECH_, DECH_);
  gemm128<1><<<gD, b256, 0, stream>>>(DECIN, WH, bd1, DECH, NT_, DECH_, DECH_);

  // ---- final combine
  final2<<<NT_, 320, 0, stream>>>(P, bo3, DECH, wd2, bd2, S1, S2,
                                  out_pred, out_dec);

  (void)in_sizes; (void)n_in; (void)out_size; (void)ws_size;
}

// Round 5
// 950.205 us; speedup vs baseline: 5.7973x; 1.1196x over previous
//
#include <hip/hip_runtime.h>
#include <cstdint>
#include <cstddef>

// Problem dims (fixed by reference)
#define NT_   8192
#define DIN_  2048
#define H_    2048
#define C_    16
#define G_    2
#define D_    256
#define WA_   35
#define DECH_ 512
#define NPAD_ 1152   // 1120 padded to 9*128

typedef _Float16 f16;
typedef _Float16 h4 __attribute__((ext_vector_type(4)));
typedef _Float16 h8 __attribute__((ext_vector_type(8)));
typedef float fx4 __attribute__((ext_vector_type(4)));

typedef __attribute__((address_space(1))) const void gvoid_t;
typedef __attribute__((address_space(3))) void lvoid_t;

// async global->LDS, 16B per lane; LDS dest = wave-uniform base + lane*16
__device__ __forceinline__ void gld16(const void* g, void* l) {
  __builtin_amdgcn_global_load_lds((gvoid_t*)(uintptr_t)g,
                                   (lvoid_t*)(uint32_t)(uintptr_t)l, 16, 0, 0);
}

__device__ __forceinline__ void barrier_() {
  asm volatile("" ::: "memory");
  __builtin_amdgcn_s_barrier();
  asm volatile("" ::: "memory");
}

template <int N>
__device__ __forceinline__ void waitvm() {
  if constexpr (N == 8)      asm volatile("s_waitcnt vmcnt(8)" ::: "memory");
  else if constexpr (N == 6) asm volatile("s_waitcnt vmcnt(6)" ::: "memory");
  else if constexpr (N == 2) asm volatile("s_waitcnt vmcnt(2)" ::: "memory");
  else                       asm volatile("s_waitcnt vmcnt(0)" ::: "memory");
}

#define MFMA_(d, a, b) d = __builtin_amdgcn_mfma_f32_16x16x32_f16(a, b, d, 0, 0, 0)

// ---------------- threefry2x32 (Random123 / JAX-compatible) ----------------
__host__ __device__ inline void tf2x32(uint32_t k0, uint32_t k1,
                                       uint32_t x0, uint32_t x1,
                                       uint32_t& o0, uint32_t& o1) {
  const uint32_t ks2 = k0 ^ k1 ^ 0x1BD11BDAu;
  uint32_t ks[3] = {k0, k1, ks2};
  x0 += ks[0]; x1 += ks[1];
  const uint32_t R0[4] = {13u, 15u, 26u, 6u};
  const uint32_t R1[4] = {17u, 29u, 16u, 24u};
#pragma unroll
  for (int g = 0; g < 5; ++g) {
    const uint32_t* R = (g & 1) ? R1 : R0;
#pragma unroll
    for (int r = 0; r < 4; ++r) {
      x0 += x1;
      x1 = (x1 << R[r]) | (x1 >> (32u - R[r]));
      x1 ^= x0;
    }
    x0 += ks[(g + 1) % 3];
    x1 += ks[(g + 2) % 3] + (uint32_t)(g + 1);
  }
  o0 = x0; o1 = x1;
}

// ---------------- x split: fp32 -> f16 hi/lo --------------------------------
__global__ __launch_bounds__(256) void xsplit_kernel(
    const float* __restrict__ x, f16* __restrict__ xh, f16* __restrict__ xl) {
  const size_t i = (size_t)blockIdx.x * 256 + threadIdx.x;  // per 8 floats
  const float4 v0 = *(const float4*)(x + i * 8);
  const float4 v1 = *(const float4*)(x + i * 8 + 4);
  float vv[8] = {v0.x, v0.y, v0.z, v0.w, v1.x, v1.y, v1.z, v1.w};
  h8 hh, ll;
#pragma unroll
  for (int k = 0; k < 8; ++k) {
    const f16 h = (f16)vv[k];
    hh[k] = h;
    ll[k] = (f16)(vv[k] - (float)h);
  }
  *(h8*)(xh + i * 8) = hh;
  *(h8*)(xl + i * 8) = ll;
}

// ============ 256x256-tile 3-term MFMA GEMM, BK=32, 8 waves =================
// A=(M,K) f16 hi/lo; B=(N,K) f16 hi/lo. 3-term: AhBh + AhBl + AlBh.
// Counted-vmcnt phased schedule: staging issue {3,3,2} across 3 phases,
// waits vmcnt(6) end-phase1 and vmcnt(2) end-of-tile (never 0 in loop).
enum { EPI_PAIR = 0, EPI_HI = 1, EPI_LOGIT = 2 };

template <int GATHER, int EPI>
__global__ __launch_bounds__(512, 2) void gemm256(
    const f16* __restrict__ Ah, const f16* __restrict__ Al,
    const f16* __restrict__ Bh, const f16* __restrict__ Bl,
    const float* __restrict__ bias,
    f16* __restrict__ Chi, f16* __restrict__ Clo,
    int M, int N, int K,
    const int* __restrict__ gidx, const float* __restrict__ growp, int gldw,
    const float* __restrict__ wlog, float* __restrict__ part) {
  extern __shared__ f16 lds[];
  constexpr int BS = 4 * 8192;  // f16 per buffer (4 regions x 16KB)

  const int tid  = threadIdx.x;
  const int wave = tid >> 6;
  const int lane = tid & 63;
  const int lr   = lane & 15;

  // bijective XCD swizzle (nwg % 8 == 0)
  const int nb  = N >> 8;
  const int nwg = (int)gridDim.x;
  const int qq  = nwg >> 3;
  const int sw  = ((int)blockIdx.x & 7) * qq + ((int)blockIdx.x >> 3);
  const int by  = sw / nb, bx = sw % nb;
  const int m0  = by << 8, n0 = bx << 8;

  const int wm = (wave >> 2) * 128;
  const int wn = (wave & 3) * 64;

  fx4 acc[8][4];
#pragma unroll
  for (int i = 0; i < 8; ++i)
#pragma unroll
    for (int j = 0; j < 4; ++j) acc[i][j] = (fx4){0.f, 0.f, 0.f, 0.f};

  // staging: one round = 512 lanes x 16B = 8KB = 128 rows x 64B
  const int r_row = wave * 16 + (lane >> 2);
  const int r_g   = (lane & 3) ^ ((lane >> 3) & 3);  // src granule swizzle
  // issue order: 0:Bh0 1:Bh1 2:Bl0 3:Bl1 4:Ah0 5:Ah1 6:Al0 7:Al1
  const f16* gsrc[8];
  int gdst[8];
  {
    int nr = 0;
    auto AR = [&](const f16* P, int mn, int reg, int rb) {
      gsrc[nr] = P + (size_t)(mn + rb + r_row) * K + r_g * 8;
      gdst[nr] = reg * 8192 + rb * 32 + wave * 512;
      ++nr;
    };
    AR(Bh, n0, 2, 0); AR(Bh, n0, 2, 128);
    AR(Bl, n0, 3, 0); AR(Bl, n0, 3, 128);
    AR(Ah, m0, 0, 0); AR(Ah, m0, 0, 128);
    AR(Al, m0, 1, 0); AR(Al, m0, 1, 128);
  }

  // prologue: stage tile 0; B+Ah must land, Al may stay in flight
#pragma unroll
  for (int r = 0; r < 8; ++r) gld16(gsrc[r], lds + gdst[r]);
  waitvm<2>();
  barrier_();

  const int pg8 = ((lane >> 4) ^ ((lr >> 1) & 3)) * 8;  // read-side swizzle
  const int KT  = K >> 5;

  for (int t = 0; t < KT; ++t) {
    f16* const sb  = lds + (t & 1) * BS;
    f16* const nsb = lds + ((t + 1) & 1) * BS;
    const int ktn = (t + 1 < KT ? t + 1 : t) * 32;  // phantom tail reload

    const f16* sAh = sb;
    const f16* sAl = sb + 8192;
    const f16* sBh = sb + 16384;
    const f16* sBl = sb + 24576;

    h8 vbh[4], vbl[4], va[4];
    // ---- phase 0: B(h,l) + Ah lower; issue Bh0,Bh1,Bl0 --------------------
#pragma unroll
    for (int j = 0; j < 4; ++j) {
      vbh[j] = *(const h8*)(sBh + (wn + j * 16 + lr) * 32 + pg8);
      vbl[j] = *(const h8*)(sBl + (wn + j * 16 + lr) * 32 + pg8);
    }
#pragma unroll
    for (int i = 0; i < 4; ++i)
      va[i] = *(const h8*)(sAh + (wm + i * 16 + lr) * 32 + pg8);
    gld16(gsrc[0] + ktn, nsb + gdst[0]);
    gld16(gsrc[1] + ktn, nsb + gdst[1]);
    gld16(gsrc[2] + ktn, nsb + gdst[2]);
    barrier_();
    asm volatile("s_waitcnt lgkmcnt(0)" ::: "memory");
    __builtin_amdgcn_sched_barrier(0);
    __builtin_amdgcn_s_setprio(1);
#pragma unroll
    for (int i = 0; i < 4; ++i)
#pragma unroll
      for (int j = 0; j < 4; ++j) MFMA_(acc[i][j], va[i], vbh[j]);
#pragma unroll
    for (int i = 0; i < 4; ++i)
#pragma unroll
      for (int j = 0; j < 4; ++j) MFMA_(acc[i][j], va[i], vbl[j]);
    __builtin_amdgcn_s_setprio(0);
    barrier_();
    // ---- phase 1: Ah upper; issue Bl1,Ah0,Ah1 ------------------------------
#pragma unroll
    for (int i = 0; i < 4; ++i)
      va[i] = *(const h8*)(sAh + (wm + 64 + i * 16 + lr) * 32 + pg8);
    gld16(gsrc[3] + ktn, nsb + gdst[3]);
    gld16(gsrc[4] + ktn, nsb + gdst[4]);
    gld16(gsrc[5] + ktn, nsb + gdst[5]);
    barrier_();
    asm volatile("s_waitcnt lgkmcnt(0)" ::: "memory");
    __builtin_amdgcn_sched_barrier(0);
    __builtin_amdgcn_s_setprio(1);
#pragma unroll
    for (int i = 0; i < 4; ++i)
#pragma unroll
      for (int j = 0; j < 4; ++j) MFMA_(acc[4 + i][j], va[i], vbh[j]);
#pragma unroll
    for (int i = 0; i < 4; ++i)
#pragma unroll
      for (int j = 0; j < 4; ++j) MFMA_(acc[4 + i][j], va[i], vbl[j]);
    __builtin_amdgcn_s_setprio(0);
    waitvm<6>();   // current tile's Al0,Al1 landed (6 newer stay in flight)
    barrier_();
    // ---- phase 2: Al x Bh (both halves); issue Al0,Al1 ---------------------
    {
      h8 vl0[4], vl1[4];
#pragma unroll
      for (int i = 0; i < 4; ++i) {
        vl0[i] = *(const h8*)(sAl + (wm + i * 16 + lr) * 32 + pg8);
        vl1[i] = *(const h8*)(sAl + (wm + 64 + i * 16 + lr) * 32 + pg8);
      }
      gld16(gsrc[6] + ktn, nsb + gdst[6]);
      gld16(gsrc[7] + ktn, nsb + gdst[7]);
      barrier_();
      asm volatile("s_waitcnt lgkmcnt(0)" ::: "memory");
      __builtin_amdgcn_sched_barrier(0);
      __builtin_amdgcn_s_setprio(1);
#pragma unroll
      for (int i = 0; i < 4; ++i)
#pragma unroll
        for (int j = 0; j < 4; ++j) {
          MFMA_(acc[i][j], vl0[i], vbh[j]);
          MFMA_(acc[4 + i][j], vl1[i], vbh[j]);
        }
      __builtin_amdgcn_s_setprio(0);
      waitvm<2>();  // next tile's B+Ah landed (Al stays in flight)
      barrier_();
    }
  }

  // ---- epilogues ----
  const int rq = (lane >> 4) * 4;
  if constexpr (EPI == EPI_LOGIT) {
    // finalize h-tile in regs: bias [+gather] + relu
#pragma unroll
    for (int mi = 0; mi < 8; ++mi) {
#pragma unroll
      for (int q = 0; q < 4; ++q) {
        const int row = m0 + wm + mi * 16 + rq + q;
        const float* gr = nullptr;
        if constexpr (GATHER) gr = growp + (size_t)gidx[row] * gldw;
#pragma unroll
        for (int j = 0; j < 4; ++j) {
          const int col = n0 + wn + j * 16 + lr;
          float v = acc[mi][j][q] + bias[col];
          if constexpr (GATHER) v += gr[col];
          acc[mi][j][q] = fmaxf(v, 0.f);
        }
      }
    }
    // drain phantom staging, then reuse LDS for coalesced PART writes
    waitvm<0>();
    barrier_();
    float* psm = (float*)lds + wave * 2560;  // 8mi x 16rows x stride20
    const int sidx = bx * 4 + (wave & 3);
    const int q_l = ((lr & 1) << 1) | ((lr >> 1) & 1);   // bitrev mapping
    const int c_l = (((lr >> 2) & 1) << 1) | ((lr >> 3) & 1);
#pragma unroll
    for (int cc = 0; cc < 4; ++cc) {
      float wc[4][4];
#pragma unroll
      for (int j = 0; j < 4; ++j) {
        const float4 wv = *(const float4*)(wlog +
            (size_t)(n0 + wn + j * 16 + lr) * 16 + cc * 4);
        wc[j][0] = wv.x; wc[j][1] = wv.y; wc[j][2] = wv.z; wc[j][3] = wv.w;
      }
#pragma unroll
      for (int mi = 0; mi < 8; ++mi) {
        float A[16];
#pragma unroll
        for (int i = 0; i < 16; ++i) {
          float s = 0.f;
#pragma unroll
          for (int j = 0; j < 4; ++j)
            s = fmaf(acc[mi][j][i >> 2], wc[j][i & 3], s);
          A[i] = s;
        }
        // distribute-reduce over the 16-lane group: lane lr ends with its
        // (q_l,c_l) total; all indices compile-time (no scratch).
#pragma unroll
        for (int k = 0; k < 4; ++k) {
          const int L2 = 8 >> k;
          const bool b = (lr >> k) & 1;
          float An[8];
#pragma unroll
          for (int i = 0; i < L2; ++i) {
            const float keep = b ? A[i + L2] : A[i];
            const float send = b ? A[i] : A[i + L2];
            An[i] = keep + __shfl_xor(send, 1 << k);
          }
#pragma unroll
          for (int i = 0; i < L2; ++i) A[i] = An[i];
        }
        psm[mi * 320 + (rq + q_l) * 20 + cc * 4 + c_l] = A[0];
      }
    }
    asm volatile("s_waitcnt lgkmcnt(0)" ::: "memory");
#pragma unroll
    for (int mi = 0; mi < 8; ++mi) {
      const float4 o = *(const float4*)(psm + mi * 320 +
                                        (lane >> 2) * 20 + (lane & 3) * 4);
      float* pout = part + ((size_t)sidx * NT_ +
                            (m0 + wm + mi * 16 + (lane >> 2))) * 16 +
                    (lane & 3) * 4;
      *(float4*)pout = o;
    }
  } else {
#pragma unroll
    for (int mi = 0; mi < 8; ++mi) {
#pragma unroll
      for (int q = 0; q < 4; ++q) {
        const int row = m0 + wm + mi * 16 + rq + q;
#pragma unroll
        for (int j = 0; j < 4; ++j) {
          const int col = n0 + wn + j * 16 + lr;
          float v = fmaxf(acc[mi][j][q] + bias[col], 0.f);
          const f16 hh = (f16)v;
          Chi[(size_t)row * N + col] = hh;
          if constexpr (EPI == EPI_PAIR)
            Clo[(size_t)row * N + col] = (f16)(v - (float)hh);
        }
      }
    }
  }
}

// ============ 256x256-tile 1-term GEMM, triple-buffered PD=2 ================
__global__ __launch_bounds__(512, 2) void gemm256_1t(
    const f16* __restrict__ Ah, const f16* __restrict__ Bh,
    const float* __restrict__ bias, f16* __restrict__ Chi,
    int M, int N, int K) {
  extern __shared__ f16 lds[];
  constexpr int BS = 16384;  // 32 KB per buffer, 3 buffers

  const int tid  = threadIdx.x;
  const int wave = tid >> 6;
  const int lane = tid & 63;
  const int lr   = lane & 15;

  const int nb  = N >> 8;
  const int nwg = (int)gridDim.x;
  const int qq  = nwg >> 3;
  const int sw  = ((int)blockIdx.x & 7) * qq + ((int)blockIdx.x >> 3);
  const int by  = sw / nb, bx = sw % nb;
  const int m0  = by << 8, n0 = bx << 8;

  const int wm = (wave >> 2) * 128;
  const int wn = (wave & 3) * 64;

  fx4 acc[8][4];
#pragma unroll
  for (int i = 0; i < 8; ++i)
#pragma unroll
    for (int j = 0; j < 4; ++j) acc[i][j] = (fx4){0.f, 0.f, 0.f, 0.f};

  const int r_row = wave * 16 + (lane >> 2);
  const int r_g   = (lane & 3) ^ ((lane >> 3) & 3);
  // regions: 0:Ah0 1:Ah1 2:Bh0 3:Bh1 (A at f16 0, B at 8192)
  const f16* gsrc[4];
  int gdst[4];
  {
    int nr = 0;
    auto AR = [&](const f16* P, int mn, int reg, int rb) {
      gsrc[nr] = P + (size_t)(mn + rb + r_row) * K + r_g * 8;
      gdst[nr] = reg * 8192 + rb * 32 + wave * 512;
      ++nr;
    };
    AR(Ah, m0, 0, 0); AR(Ah, m0, 0, 128);
    AR(Bh, n0, 1, 0); AR(Bh, n0, 1, 128);
  }

  const int KT  = K >> 5;
  const int pg8 = ((lane >> 4) ^ ((lr >> 1) & 3)) * 8;

  // prologue: tiles 0 and 1
#pragma unroll
  for (int r = 0; r < 4; ++r) gld16(gsrc[r], lds + gdst[r]);
#pragma unroll
  for (int r = 0; r < 4; ++r) gld16(gsrc[r] + 32, lds + BS + gdst[r]);

  int cur = 0, nn = 2;
  for (int t = 0; t < KT; ++t) {
    const int ktn = (t + 2 < KT ? t + 2 : KT - 1) * 32;
    f16* const nsb = lds + nn * BS;
#pragma unroll
    for (int r = 0; r < 4; ++r) gld16(gsrc[r] + ktn, nsb + gdst[r]);
    waitvm<8>();  // tile t's 4 loads landed; t+1/t+2's 8 stay in flight
    barrier_();

    const f16* sb = lds + cur * BS;
    h8 vb[4], va0[4], va1[4];
#pragma unroll
    for (int j = 0; j < 4; ++j)
      vb[j] = *(const h8*)(sb + 8192 + (wn + j * 16 + lr) * 32 + pg8);
#pragma unroll
    for (int i = 0; i < 4; ++i) {
      va0[i] = *(const h8*)(sb + (wm + i * 16 + lr) * 32 + pg8);
      va1[i] = *(const h8*)(sb + (wm + 64 + i * 16 + lr) * 32 + pg8);
    }
    asm volatile("s_waitcnt lgkmcnt(0)" ::: "memory");
    __builtin_amdgcn_sched_barrier(0);
    __builtin_amdgcn_s_setprio(1);
#pragma unroll
    for (int i = 0; i < 4; ++i)
#pragma unroll
      for (int j = 0; j < 4; ++j) {
        MFMA_(acc[i][j], va0[i], vb[j]);
        MFMA_(acc[4 + i][j], va1[i], vb[j]);
      }
    __builtin_amdgcn_s_setprio(0);
    barrier_();
    cur = (cur == 2) ? 0 : cur + 1;
    nn  = (nn == 2) ? 0 : nn + 1;
  }

  const int rq = (lane >> 4) * 4;
#pragma unroll
  for (int mi = 0; mi < 8; ++mi) {
#pragma unroll
    for (int q = 0; q < 4; ++q) {
      const int row = m0 + wm + mi * 16 + rq + q;
#pragma unroll
      for (int j = 0; j < 4; ++j) {
        const int col = n0 + wn + j * 16 + lr;
        Chi[(size_t)row * N + col] = (f16)fmaxf(acc[mi][j][q] + bias[col], 0.f);
      }
    }
  }
}

// ============== 128x128 MFMA GEMM (kept for wo3-P and wd1) =================
template <int RELU>
__global__ __launch_bounds__(256, 2) void gemm128(
    const f16* __restrict__ Ah, const f16* __restrict__ Bh,
    const float* __restrict__ bias, f16* __restrict__ Chi,
    int M, int N, int K) {
  __shared__ f16 lds[2 * 4096];
  f16* sAh = lds;
  f16* sBh = lds + 4096;

  const int tid  = threadIdx.x;
  const int wave = tid >> 6;
  const int lane = tid & 63;
  const int n0 = blockIdx.x * 128;
  const int m0 = blockIdx.y * 128;
  const int wm = (wave >> 1) * 64;
  const int wn = (wave & 1) * 64;
  const int lr = lane & 15;
  const int lk = (lane >> 4) * 8;

  fx4 acc[4][4];
#pragma unroll
  for (int i = 0; i < 4; ++i)
#pragma unroll
    for (int j = 0; j < 4; ++j) acc[i][j] = (fx4){0.f, 0.f, 0.f, 0.f};

  const int sb = wave * 2048 + (lane << 4);

  for (int kt = 0; kt < K; kt += 32) {
#pragma unroll
    for (int c = 0; c < 2; ++c) {
      const int boff = sb + c * 1024;
      const int row  = boff >> 6;
      const int col  = (boff & 63) >> 1;
      gld16(Bh + (size_t)(n0 + row) * K + kt + col, sBh + (wave * 2 + c) * 512);
      gld16(Ah + (size_t)(m0 + row) * K + kt + col, sAh + (wave * 2 + c) * 512);
    }
    __syncthreads();

    h8 ah[4], bh[4];
#pragma unroll
    for (int t = 0; t < 4; ++t) {
      ah[t] = *(const h8*)&sAh[(wm + t * 16 + lr) * 32 + lk];
      bh[t] = *(const h8*)&sBh[(wn + t * 16 + lr) * 32 + lk];
    }
#pragma unroll
    for (int i = 0; i < 4; ++i)
#pragma unroll
      for (int j = 0; j < 4; ++j) MFMA_(acc[i][j], ah[i], bh[j]);
    __syncthreads();
  }

  const int rq = (lane >> 4) * 4;
#pragma unroll
  for (int i = 0; i < 4; ++i) {
#pragma unroll
    for (int q = 0; q < 4; ++q) {
      const int row = m0 + wm + i * 16 + rq + q;
#pragma unroll
      for (int j = 0; j < 4; ++j) {
        const int col = n0 + wn + j * 16 + lr;
        float v = acc[i][j][q];
        if (bias) v += bias[col];
        if constexpr (RELU) v = fmaxf(v, 0.f);
        Chi[(size_t)row * N + col] = (f16)v;
      }
    }
  }
}

// ====== weight transpose+convert: (K,N) fp32 -> (Npad,K) f16 hi[/lo] =======
template <int SPLIT>
__global__ __launch_bounds__(256) void wtransT(
    const float* __restrict__ src, f16* __restrict__ hi, f16* __restrict__ lo,
    int K, int N, int Npad) {
  __shared__ float t[32][33];
  const int bn = blockIdx.x * 32;
  const int bk = blockIdx.y * 32;
  const int tx = threadIdx.x & 31, ty = threadIdx.x >> 5;
#pragma unroll
  for (int r = ty; r < 32; r += 8) {
    const float v = (bn + tx < N) ? src[(size_t)(bk + r) * N + bn + tx] : 0.f;
    t[tx][r] = v;
  }
  __syncthreads();
#pragma unroll
  for (int r = ty; r < 32; r += 8) {
    const float v = t[r][tx];
    const f16 hh = (f16)v;
    hi[(size_t)(bn + r) * K + bk + tx] = hh;
    if (SPLIT) lo[(size_t)(bn + r) * K + bk + tx] = (f16)(v - (float)hh);
  }
}

// ====== reduce partials + bias -> logits; fused JAX categorical sample =====
__global__ __launch_bounds__(256) void reduce_sample(
    const float* __restrict__ part, const float* __restrict__ bias,
    float* __restrict__ logits_out, int* __restrict__ s_out,
    float* __restrict__ centers_out, uint32_t ka, uint32_t kb, int which) {
  const int tid = threadIdx.x;
  const int c = tid & 15;
  const int m = blockIdx.x * 16 + (tid >> 4);
  float v = bias[c];
#pragma unroll 8
  for (int s = 0; s < 32; ++s) v += part[((size_t)s * NT_ + m) * 16 + c];
  logits_out[(size_t)m * C_ + c] = v;
  // gumbel (JAX threefry bits, partitionable path)
  const uint32_t j = (uint32_t)(m * C_ + c);
  uint32_t o0, o1;
  tf2x32(ka, kb, 0u, j, o0, o1);
  const uint32_t bits = o0 ^ o1;
  float u = __uint_as_float((bits >> 9) | 0x3f800000u) - 1.0f;
  u = fmaxf(1.17549435e-38f, u);
  float z = -logf(-logf(u)) + v;
  int bi = c;
#pragma unroll
  for (int st = 1; st < 16; st <<= 1) {
    const float oz = __shfl_xor(z, st);
    const int   ob = __shfl_xor(bi, st);
    if (oz > z || (oz == z && ob < bi)) { z = oz; bi = ob; }
  }
  if (c == 0) {
    s_out[m] = bi;
    centers_out[(size_t)m * G_ + which] = (float)bi;
  }
}

// ---------------- dec_in gather: codebook rows -> f16 ----------------------
__global__ void gather_dec_kernel(const float* __restrict__ codebook,
                                  const int* __restrict__ s1,
                                  const int* __restrict__ s2,
                                  f16* __restrict__ dec_in) {
  const int idx = blockIdx.x * blockDim.x + threadIdx.x;
  const int m = idx >> 9, d = idx & 511;
  const int g = d >> 8, dd = d & 255;
  const int s = g ? s2[m] : s1[m];
  dec_in[idx] = (f16)codebook[(size_t)(g * C_ + s) * D_ + dd];
}

// ------- final: decoded = dec_h@wd2+bd2 ; pred = decoded + P gather --------
__global__ __launch_bounds__(320) void final2(
    const f16* __restrict__ P,
    const float* __restrict__ bo3,
    const f16* __restrict__ dech,
    const float* __restrict__ wd2, const float* __restrict__ bd2,
    const int* __restrict__ s1, const int* __restrict__ s2,
    float* __restrict__ out_pred, float* __restrict__ out_dec) {
  __shared__ float drow[DECH_];
  const int m = blockIdx.x;
  for (int i = threadIdx.x; i < DECH_; i += 320)
    drow[i] = (float)dech[(size_t)m * DECH_ + i];
  __syncthreads();
  const int a1 = s1[m], a2 = s2[m];
  const int c = threadIdx.x >> 3, g = threadIdx.x & 7;
  float pdec = 0.f;
  if (c < WA_) {
    for (int i = 0; i < DECH_ / 8; ++i) {
      const int k = g * (DECH_ / 8) + i;
      pdec = fmaf(drow[k], wd2[(size_t)k * WA_ + c], pdec);
    }
  }
#pragma unroll
  for (int off = 1; off < 8; off <<= 1) pdec += __shfl_xor(pdec, off);
  if (c < WA_ && g == 0) {
    const float dec = pdec + bd2[c];
    const float soff = (float)P[(size_t)m * NPAD_ + a1 * WA_ + c]
                     + (float)P[(size_t)m * NPAD_ + C_ * WA_ + a2 * WA_ + c]
                     + bo3[a1 * WA_ + c] + bo3[C_ * WA_ + a2 * WA_ + c];
    out_dec[(size_t)m * WA_ + c] = dec;
    out_pred[(size_t)m * WA_ + c] = dec + soff;
  }
}

// ---------------------------------------------------------------------------
extern "C" void kernel_launch(void* const* d_in, const int* in_sizes, int n_in,
                              void* d_out, int out_size, void* d_ws, size_t ws_size,
                              hipStream_t stream) {
  const float* x    = (const float*)d_in[0];
  const float* w11  = (const float*)d_in[1];
  const float* b11  = (const float*)d_in[2];
  const float* w12  = (const float*)d_in[3];
  const float* b12  = (const float*)d_in[4];
  const float* w13  = (const float*)d_in[5];
  const float* b13  = (const float*)d_in[6];
  const float* w21  = (const float*)d_in[7];
  const float* b21  = (const float*)d_in[8];
  const float* w22  = (const float*)d_in[9];
  const float* b22  = (const float*)d_in[10];
  const float* wo1  = (const float*)d_in[11];
  const float* bo1  = (const float*)d_in[12];
  const float* wo2  = (const float*)d_in[13];
  const float* bo2  = (const float*)d_in[14];
  const float* wo3  = (const float*)d_in[15];
  const float* bo3  = (const float*)d_in[16];
  const float* cbk  = (const float*)d_in[17];
  const float* wd1  = (const float*)d_in[18];
  const float* bd1  = (const float*)d_in[19];
  const float* wd2  = (const float*)d_in[20];
  const float* bd2  = (const float*)d_in[21];

  float* out = (float*)d_out;
  float* out_pred = out;
  float* out_dec  = out + (size_t)NT_ * WA_;
  float* out_l1   = out + (size_t)2 * NT_ * WA_;
  float* out_l2   = out_l1 + (size_t)NT_ * C_;
  float* out_sc   = out_l2 + (size_t)NT_ * C_;

  // workspace layout (~161 MB)
  const size_t AB = (size_t)NT_ * H_;
  f16*   Xh   = (f16*)d_ws;                       // (NT,2048) f16
  f16*   Xl   = Xh + AB;
  f16*   H1a  = Xl + AB;                          // h1-hi | o1
  f16*   H1b  = H1a + AB;                         // h1-lo | o2
  f16*   WH   = H1b + AB;                         // (2048,2048) f16
  f16*   WL   = WH + (size_t)H_ * H_;
  float* PART = (float*)(WL + (size_t)H_ * H_);   // (32, NT, 16) fp32
  int*   S1   = (int*)(PART + (size_t)32 * NT_ * C_);
  int*   S2   = S1 + NT_;

  f16* O1    = H1a;
  f16* O2    = H1b;
  f16* P     = Xh;                                // after wo1, Xh is dead
  f16* DECIN = Xl;                                // after w21, Xl is dead
  f16* DECH  = Xl + (size_t)NT_ * DECH_;

  hipFuncSetAttribute(reinterpret_cast<const void*>(&gemm256<0,EPI_PAIR>),
                      hipFuncAttributeMaxDynamicSharedMemorySize, 131072);
  hipFuncSetAttribute(reinterpret_cast<const void*>(&gemm256<0,EPI_LOGIT>),
                      hipFuncAttributeMaxDynamicSharedMemorySize, 131072);
  hipFuncSetAttribute(reinterpret_cast<const void*>(&gemm256<1,EPI_LOGIT>),
                      hipFuncAttributeMaxDynamicSharedMemorySize, 131072);
  hipFuncSetAttribute(reinterpret_cast<const void*>(&gemm256_1t),
                      hipFuncAttributeMaxDynamicSharedMemorySize, 98304);

  // subkeys of jax.random.split(jax.random.key(42)); key data = [0,42]
  uint32_t k1a, k1b, k2a, k2b;
  tf2x32(0u, 42u, 0u, 0u, k1a, k1b);
  tf2x32(0u, 42u, 0u, 1u, k2a, k2b);

  const dim3 b256(256), b512(512);
  const dim3 gW(H_ / 32, H_ / 32);
  const dim3 gWo3(NPAD_ / 32, H_ / 32);
  const dim3 gWd1(DECH_ / 32, DECH_ / 32);
  const dim3 gBig((NT_ / 256) * (H_ / 256));   // 256 blocks
  const dim3 gP(NPAD_ / 128, NT_ / 128);
  const dim3 gD(DECH_ / 128, NT_ / 128);

  // ---- x -> hi/lo split (once; feeds w11, w21)
  xsplit_kernel<<<NT_ * H_ / (8 * 256), b256, 0, stream>>>(x, Xh, Xl);

  // ---- bin1: h1 = relu(x@w11+b11); logits1 = relu(h1@w12+b12)@w13+b13
  wtransT<1><<<gW, b256, 0, stream>>>(w11, WH, WL, H_, H_, H_);
  gemm256<0,EPI_PAIR><<<gBig, b512, 131072, stream>>>(
      Xh, Xl, WH, WL, b11, H1a, H1b, NT_, H_, DIN_,
      nullptr, nullptr, 0, nullptr, nullptr);
  wtransT<1><<<gW, b256, 0, stream>>>(w12, WH, WL, H_, H_, H_);
  gemm256<0,EPI_LOGIT><<<gBig, b512, 131072, stream>>>(
      H1a, H1b, WH, WL, b12, nullptr, nullptr, NT_, H_, H_,
      nullptr, nullptr, 0, w13, PART);
  reduce_sample<<<NT_ / 16, b256, 0, stream>>>(PART, b13, out_l1, S1, out_sc,
                                               k1a, k1b, 0);

  // ---- bin2: logits2 = relu(x@w21[:2048] + w21[2048+s1] + b21)@w22+b22
  wtransT<1><<<gW, b256, 0, stream>>>(w21, WH, WL, H_, H_, H_);
  gemm256<1,EPI_LOGIT><<<gBig, b512, 131072, stream>>>(
      Xh, Xl, WH, WL, b21, nullptr, nullptr, NT_, H_, DIN_,
      S1, w21 + (size_t)DIN_ * H_, H_, w22, PART);
  reduce_sample<<<NT_ / 16, b256, 0, stream>>>(PART, b22, out_l2, S2, out_sc,
                                               k2a, k2b, 1);

  // ---- offsets: o1 = relu(x@wo1+bo1); o2 = relu(o1@wo2+bo2); P = o2@wo3
  wtransT<0><<<gW, b256, 0, stream>>>(wo1, WH, nullptr, H_, H_, H_);
  gemm256_1t<<<gBig, b512, 98304, stream>>>(Xh, WH, bo1, O1, NT_, H_, DIN_);
  wtransT<0><<<gW, b256, 0, stream>>>(wo2, WH, nullptr, H_, H_, H_);
  gemm256_1t<<<gBig, b512, 98304, stream>>>(O1, WH, bo2, O2, NT_, H_, H_);
  wtransT<0><<<gWo3, b256, 0, stream>>>(wo3, WH, nullptr, H_, G_ * C_ * WA_, NPAD_);
  gemm128<0><<<gP, b256, 0, stream>>>(O2, WH, nullptr, P, NT_, NPAD_, H_);

  // ---- decoder: dec_h = relu(dec_in@wd1+bd1)
  gather_dec_kernel<<<(NT_ * DECH_) / 256, b256, 0, stream>>>(cbk, S1, S2, DECIN);
  wtransT<0><<<gWd1, b256, 0, stream>>>(wd1, WH, nullptr, DECH_, DECH_, DECH_);
  gemm128<1><<<gD, b256, 0, stream>>>(DECIN, WH, bd1, DECH, NT_, DECH_, DECH_);

  // ---- final combine
  final2<<<NT_, 320, 0, stream>>>(P, bo3, DECH, wd2, bd2, S1, S2,
                                  out_pred, out_dec);

  (void)in_sizes; (void)n_in; (void)out_size; (void)ws_size;
}